// Round 3
// baseline (262.014 us; speedup 1.0000x reference)
//
#include <hip/hip_runtime.h>
#include <math.h>

#define B_ 2
#define N_ 20000
#define C_ 64
#define K_ 16
#define CS_ 16
#define EPS_ 1e-5f

// ---------------------------------------------------------------------------
// Kernel A: 1x1 conv projections, tiled mini-GEMM (unchanged from R2).
// Output layout [B*N][C] so kernel B's gathers read 256B-contiguous rows.
// ---------------------------------------------------------------------------
__device__ __forceinline__ void mv16(const float* __restrict__ W,
                                     const float* __restrict__ bias,
                                     int ob, const float (&x)[C_], float (&acc)[16])
{
#pragma unroll
    for (int jg = 0; jg < 4; jg++) {
        const float* r0 = W + (size_t)(ob + jg * 4) * C_;
        const float* r1 = r0 + C_;
        const float* r2 = r0 + 2 * C_;
        const float* r3 = r0 + 3 * C_;
        float a0 = bias[ob + jg * 4 + 0];
        float a1 = bias[ob + jg * 4 + 1];
        float a2 = bias[ob + jg * 4 + 2];
        float a3 = bias[ob + jg * 4 + 3];
#pragma unroll
        for (int ci = 0; ci < C_; ci++) {
            float xc = x[ci];
            a0 = fmaf(r0[ci], xc, a0);
            a1 = fmaf(r1[ci], xc, a1);
            a2 = fmaf(r2[ci], xc, a2);
            a3 = fmaf(r3[ci], xc, a3);
        }
        acc[jg * 4 + 0] = a0; acc[jg * 4 + 1] = a1;
        acc[jg * 4 + 2] = a2; acc[jg * 4 + 3] = a3;
    }
}

__global__ __launch_bounds__(256) void proj_kernel(
    const float* __restrict__ q, const float* __restrict__ kin,
    const float* __restrict__ wq, const float* __restrict__ bq,
    const float* __restrict__ wk, const float* __restrict__ bk,
    const float* __restrict__ wv, const float* __restrict__ bv,
    float* __restrict__ xq_t, float* __restrict__ xk_t, float* __restrict__ xv_t)
{
    __shared__ float tin[C_][65];
    __shared__ float tout[C_][65];

    const int t      = threadIdx.x;
    const int lane_p = t & 63;
    const int pt0    = blockIdx.x * 64;
    const int pt     = pt0 + lane_p;
    const int b      = pt / N_;
    const int n      = pt - b * N_;
    const size_t cbase = (size_t)b * C_ * N_ + n;

    const int oq = __builtin_amdgcn_readfirstlane(t >> 6);
    const int ob = oq * 16;

    const int s_p  = t >> 2;
    const int s_c0 = (t & 3) * 16;

#pragma unroll
    for (int r = 0; r < 16; r++) {
        int ci = ob + r;
        tin[ci][lane_p] = q[cbase + (size_t)ci * N_];
    }
    __syncthreads();

    float x[C_];
#pragma unroll
    for (int ci = 0; ci < C_; ci++) x[ci] = tin[ci][lane_p];

    float accq[16], accv[16];
    mv16(wq, bq, ob, x, accq);
    mv16(wv, bv, ob, x, accv);

#pragma unroll
    for (int j = 0; j < 16; j++) tout[ob + j][lane_p] = accq[j];
    __syncthreads();
    {
        float4* dp = reinterpret_cast<float4*>(xq_t + (size_t)(pt0 + s_p) * C_ + s_c0);
#pragma unroll
        for (int j4 = 0; j4 < 4; j4++) {
            float4 v;
            v.x = tout[s_c0 + j4 * 4 + 0][s_p];
            v.y = tout[s_c0 + j4 * 4 + 1][s_p];
            v.z = tout[s_c0 + j4 * 4 + 2][s_p];
            v.w = tout[s_c0 + j4 * 4 + 3][s_p];
            dp[j4] = v;
        }
    }
    __syncthreads();

#pragma unroll
    for (int j = 0; j < 16; j++) tout[ob + j][lane_p] = accv[j];
    __syncthreads();
    {
        float4* dp = reinterpret_cast<float4*>(xv_t + (size_t)(pt0 + s_p) * C_ + s_c0);
#pragma unroll
        for (int j4 = 0; j4 < 4; j4++) {
            float4 v;
            v.x = tout[s_c0 + j4 * 4 + 0][s_p];
            v.y = tout[s_c0 + j4 * 4 + 1][s_p];
            v.z = tout[s_c0 + j4 * 4 + 2][s_p];
            v.w = tout[s_c0 + j4 * 4 + 3][s_p];
            dp[j4] = v;
        }
    }
    __syncthreads();

#pragma unroll
    for (int r = 0; r < 16; r++) {
        int ci = ob + r;
        tin[ci][lane_p] = kin[cbase + (size_t)ci * N_];
    }
    __syncthreads();
#pragma unroll
    for (int ci = 0; ci < C_; ci++) x[ci] = tin[ci][lane_p];

    float acck[16];
    mv16(wk, bk, ob, x, acck);
#pragma unroll
    for (int j = 0; j < 16; j++) tout[ob + j][lane_p] = acck[j];
    __syncthreads();
    {
        float4* dp = reinterpret_cast<float4*>(xk_t + (size_t)(pt0 + s_p) * C_ + s_c0);
#pragma unroll
        for (int j4 = 0; j4 < 4; j4++) {
            float4 v;
            v.x = tout[s_c0 + j4 * 4 + 0][s_p];
            v.y = tout[s_c0 + j4 * 4 + 1][s_p];
            v.z = tout[s_c0 + j4 * 4 + 2][s_p];
            v.w = tout[s_c0 + j4 * 4 + 3][s_p];
            dp[j4] = v;
        }
    }
}

// ---------------------------------------------------------------------------
// Kernel B: per-point attention. 4 points per 256-thread block, ONE WAVE per
// point — no __syncthreads, wave-private LDS slices, compiler-only fences
// (same-wave DS ops are processed in order by the LDS pipe).
//   LDS/point: wbuf 16x68 (4352B) + zs 16x17 (1088B, z then softmax reuse)
//   v held in 16 registers (written and read by the same lane).
// 21760 B/block -> 7 blocks/CU -> 28 waves/CU if VGPR<=72.
// ---------------------------------------------------------------------------
__device__ __forceinline__ void wave_fence()
{
    __builtin_amdgcn_wave_barrier();       // compiler scheduling fence
}

__global__ __launch_bounds__(256, 7) void attn_kernel(
    const float* __restrict__ coord, const int* __restrict__ nbr,
    const float* __restrict__ xq_t, const float* __restrict__ xk_t,
    const float* __restrict__ xv_t,
    const float* __restrict__ p1_w, const float* __restrict__ p1_b,
    const float* __restrict__ p_bn_g, const float* __restrict__ p_bn_b,
    const float* __restrict__ p_bn_m, const float* __restrict__ p_bn_v,
    const float* __restrict__ p2_w, const float* __restrict__ p2_b,
    const float* __restrict__ w_bn1_g, const float* __restrict__ w_bn1_b,
    const float* __restrict__ w_bn1_m, const float* __restrict__ w_bn1_v,
    const float* __restrict__ w1_w, const float* __restrict__ w1_b,
    const float* __restrict__ w_bn2_g, const float* __restrict__ w_bn2_b,
    const float* __restrict__ w_bn2_m, const float* __restrict__ w_bn2_v,
    const float* __restrict__ w2_w, const float* __restrict__ w2_b,
    float* __restrict__ out_t)
{
    constexpr int WS = 68;                    // wbuf row stride (16B-aligned rows)
    constexpr int ZS = 17;                    // z/softmax row stride
    constexpr int PW = K_ * WS + K_ * ZS;     // floats per wave slice (1360)
    __shared__ float lds[4 * PW];             // 21760 B

    const int w  = __builtin_amdgcn_readfirstlane(threadIdx.x >> 6);
    const int c  = threadIdx.x & 63;
    const int bn = blockIdx.x * 4 + w;        // grid 10000 * 4 = 40000 exact
    const int b  = bn / N_;
    const int bB = b * N_;

    float* wbuf = lds + w * PW;
    float* zs   = wbuf + K_ * WS;

    // per-lane constants, BN affine folded
    float xq   = xq_t[(size_t)bn * C_ + c];
    float p2w0 = p2_w[c * 3 + 0], p2w1 = p2_w[c * 3 + 1], p2w2 = p2_w[c * 3 + 2];
    float p2b  = p2_b[c];
    float bn1s = w_bn1_g[c] * rsqrtf(w_bn1_v[c] + EPS_);
    float bn1b = w_bn1_b[c] - w_bn1_m[c] * bn1s;

    float p1w[9], pbs[3], pbb[3];             // wave-uniform -> SGPRs
#pragma unroll
    for (int j = 0; j < 9; j++) p1w[j] = p1_w[j];
#pragma unroll
    for (int j = 0; j < 3; j++) {
        float s = p_bn_g[j] * rsqrtf(p_bn_v[j] + EPS_);
        pbs[j] = s;
        pbb[j] = (p1_b[j] - p_bn_m[j]) * s + p_bn_b[j];
    }

    // ---- phase 1: batched gather ----
    const int* nb = nbr + (size_t)bn * K_;
    int idxs[K_];
#pragma unroll
    for (int kk = 0; kk < K_; kk++) idxs[kk] = nb[kk];    // uniform -> s_load

    float xks[K_], xvs[K_];
#pragma unroll
    for (int kk = 0; kk < K_; kk++) {
        int src = bB + idxs[kk];
        xks[kk] = xk_t[(size_t)src * C_ + c];             // coalesced 256B rows
        xvs[kk] = xv_t[(size_t)src * C_ + c];
    }

    float vreg[K_];
#pragma unroll
    for (int kk = 0; kk < K_; kk++) {
        int src = bB + idxs[kk];
        const float* cp = coord + (size_t)src * 3;        // uniform -> s_load
        float cx = cp[0], cy = cp[1], cz = cp[2];
        float h0 = fmaxf(0.f, (p1w[0]*cx + p1w[1]*cy + p1w[2]*cz) * pbs[0] + pbb[0]);
        float h1 = fmaxf(0.f, (p1w[3]*cx + p1w[4]*cy + p1w[5]*cz) * pbs[1] + pbb[1]);
        float h2 = fmaxf(0.f, (p1w[6]*cx + p1w[7]*cy + p1w[8]*cz) * pbs[2] + pbb[2]);
        float pr = fmaf(p2w0, h0, fmaf(p2w1, h1, fmaf(p2w2, h2, p2b)));
        wbuf[kk * WS + c] = fmaxf(0.f, (xks[kk] - xq + pr) * bn1s + bn1b);
        vreg[kk] = xvs[kk] + pr;
    }
    wave_fence();

    // ---- phase 2a: u[g, k] = w1_w[g,:] . wbuf[k,:] ----
    const int g  = c & 15;
    const int kb = (c >> 4) * 4;
    float u0 = 0.f, u1 = 0.f, u2 = 0.f, u3 = 0.f;
    const float4* w1r = reinterpret_cast<const float4*>(w1_w + g * C_);
#pragma unroll
    for (int c4 = 0; c4 < 16; c4++) {
        float4 wr = w1r[c4];
        float4 b0 = *reinterpret_cast<const float4*>(&wbuf[(kb + 0) * WS + c4 * 4]);
        float4 b1 = *reinterpret_cast<const float4*>(&wbuf[(kb + 1) * WS + c4 * 4]);
        float4 b2 = *reinterpret_cast<const float4*>(&wbuf[(kb + 2) * WS + c4 * 4]);
        float4 b3 = *reinterpret_cast<const float4*>(&wbuf[(kb + 3) * WS + c4 * 4]);
        u0 = fmaf(wr.x, b0.x, u0); u0 = fmaf(wr.y, b0.y, u0); u0 = fmaf(wr.z, b0.z, u0); u0 = fmaf(wr.w, b0.w, u0);
        u1 = fmaf(wr.x, b1.x, u1); u1 = fmaf(wr.y, b1.y, u1); u1 = fmaf(wr.z, b1.z, u1); u1 = fmaf(wr.w, b1.w, u1);
        u2 = fmaf(wr.x, b2.x, u2); u2 = fmaf(wr.y, b2.y, u2); u2 = fmaf(wr.z, b2.z, u2); u2 = fmaf(wr.w, b2.w, u2);
        u3 = fmaf(wr.x, b3.x, u3); u3 = fmaf(wr.y, b3.y, u3); u3 = fmaf(wr.z, b3.z, u3); u3 = fmaf(wr.w, b3.w, u3);
    }
    float w1bb = w1_b[g];
    float bn2s = w_bn2_g[g] * rsqrtf(w_bn2_v[g] + EPS_);
    float bn2b = w_bn2_b[g] - w_bn2_m[g] * bn2s;
    zs[(kb + 0) * ZS + g] = fmaxf(0.f, (u0 + w1bb) * bn2s + bn2b);
    zs[(kb + 1) * ZS + g] = fmaxf(0.f, (u1 + w1bb) * bn2s + bn2b);
    zs[(kb + 2) * ZS + g] = fmaxf(0.f, (u2 + w1bb) * bn2s + bn2b);
    zs[(kb + 3) * ZS + g] = fmaxf(0.f, (u3 + w1bb) * bn2s + bn2b);
    wave_fence();

    // ---- phase 2b: t[g, k] = w2_b[g] + sum_gg w2_w[g,gg] * z[gg, k] ----
    float t0 = w2_b[g], t1 = t0, t2 = t0, t3 = t0;
#pragma unroll
    for (int gg = 0; gg < 16; gg++) {
        float w2 = w2_w[g * 16 + gg];
        t0 = fmaf(w2, zs[(kb + 0) * ZS + gg], t0);
        t1 = fmaf(w2, zs[(kb + 1) * ZS + gg], t1);
        t2 = fmaf(w2, zs[(kb + 2) * ZS + gg], t2);
        t3 = fmaf(w2, zs[(kb + 3) * ZS + gg], t3);
    }
    wave_fence();   // all z reads issued before softmax overwrites zs

    // softmax over the 16 k's: 4 local + lanes {g, g+16, g+32, g+48}
    float m = fmaxf(fmaxf(t0, t1), fmaxf(t2, t3));
    m = fmaxf(m, __shfl_xor(m, 16));
    m = fmaxf(m, __shfl_xor(m, 32));
    float e0 = expf(t0 - m), e1 = expf(t1 - m), e2 = expf(t2 - m), e3 = expf(t3 - m);
    float s = e0 + e1 + e2 + e3;
    s += __shfl_xor(s, 16);
    s += __shfl_xor(s, 32);
    float inv = 1.0f / s;
    zs[(kb + 0) * ZS + g] = e0 * inv;   // reuse zs for softmax weights
    zs[(kb + 1) * ZS + g] = e1 * inv;
    zs[(kb + 2) * ZS + g] = e2 * inv;
    zs[(kb + 3) * ZS + g] = e3 * inv;
    wave_fence();

    // ---- phase 3: out[c] = sum_k vreg[k] * soft[k][c & 15] ----
    float acc = 0.f;
#pragma unroll
    for (int kk = 0; kk < K_; kk++)
        acc = fmaf(vreg[kk], zs[kk * ZS + g], acc);
    out_t[(size_t)bn * C_ + c] = acc;   // coalesced [point][channel]
}

// ---------------------------------------------------------------------------
// Kernel C: transpose [B, N, C] -> [B, C, N], 64x64 LDS tiles.
// ---------------------------------------------------------------------------
__global__ __launch_bounds__(256) void transpose_kernel(const float* __restrict__ src,
                                                        float* __restrict__ dst)
{
    __shared__ float tile[64][65];
    int b  = blockIdx.y;
    int n0 = blockIdx.x * 64;
    int t  = threadIdx.x;

    int p  = t >> 2;
    int c0 = (t & 3) * 16;
    int n  = n0 + p;
    if (n < N_) {
        const float4* s = reinterpret_cast<const float4*>(src + ((size_t)b * N_ + n) * C_ + c0);
#pragma unroll
        for (int j = 0; j < 4; j++) {
            float4 v = s[j];
            tile[p][c0 + j * 4 + 0] = v.x;
            tile[p][c0 + j * 4 + 1] = v.y;
            tile[p][c0 + j * 4 + 2] = v.z;
            tile[p][c0 + j * 4 + 3] = v.w;
        }
    }
    __syncthreads();

    int n_off = t & 63;
    int cg    = t >> 6;
    if (n0 + n_off < N_) {
#pragma unroll
        for (int j = 0; j < 16; j++) {
            int cc = cg * 16 + j;
            dst[(size_t)b * C_ * N_ + (size_t)cc * N_ + n0 + n_off] = tile[n_off][cc];
        }
    }
}

// ---------------------------------------------------------------------------
extern "C" void kernel_launch(void* const* d_in, const int* in_sizes, int n_in,
                              void* d_out, int out_size, void* d_ws, size_t ws_size,
                              hipStream_t stream)
{
    const float* coord = (const float*)d_in[0];
    const float* q     = (const float*)d_in[1];
    const float* k     = (const float*)d_in[2];
    const int*   nbr   = (const int*)d_in[3];
    const float* wq = (const float*)d_in[4];
    const float* bq = (const float*)d_in[5];
    const float* wk = (const float*)d_in[6];
    const float* bk = (const float*)d_in[7];
    const float* wv = (const float*)d_in[8];
    const float* bv = (const float*)d_in[9];
    const float* p1_w = (const float*)d_in[10];
    const float* p1_b = (const float*)d_in[11];
    const float* p_bn_g = (const float*)d_in[12];
    const float* p_bn_b = (const float*)d_in[13];
    const float* p_bn_m = (const float*)d_in[14];
    const float* p_bn_v = (const float*)d_in[15];
    const float* p2_w = (const float*)d_in[16];
    const float* p2_b = (const float*)d_in[17];
    const float* w_bn1_g = (const float*)d_in[18];
    const float* w_bn1_b = (const float*)d_in[19];
    const float* w_bn1_m = (const float*)d_in[20];
    const float* w_bn1_v = (const float*)d_in[21];
    const float* w1_w = (const float*)d_in[22];
    const float* w1_b = (const float*)d_in[23];
    const float* w_bn2_g = (const float*)d_in[24];
    const float* w_bn2_b = (const float*)d_in[25];
    const float* w_bn2_m = (const float*)d_in[26];
    const float* w_bn2_v = (const float*)d_in[27];
    const float* w2_w = (const float*)d_in[28];
    const float* w2_b = (const float*)d_in[29];

    const size_t PTS = (size_t)B_ * N_;        // 40000
    float* ws   = (float*)d_ws;
    float* xq_t = ws;                          // [PTS][64]
    float* xk_t = ws + PTS * C_;               // [PTS][64]
    float* xv_t = ws + 2 * PTS * C_;           // [PTS][64]
    float* out_t = xq_t;  // safe alias: wave bn reads xq_t[bn] before writing out_t[bn]

    proj_kernel<<<(B_ * N_) / 64, 256, 0, stream>>>(
        q, k, wq, bq, wk, bk, wv, bv, xq_t, xk_t, xv_t);

    attn_kernel<<<(B_ * N_) / 4, 256, 0, stream>>>(
        coord, nbr, xq_t, xk_t, xv_t,
        p1_w, p1_b, p_bn_g, p_bn_b, p_bn_m, p_bn_v, p2_w, p2_b,
        w_bn1_g, w_bn1_b, w_bn1_m, w_bn1_v, w1_w, w1_b,
        w_bn2_g, w_bn2_b, w_bn2_m, w_bn2_v, w2_w, w2_b,
        out_t);

    transpose_kernel<<<dim3((N_ + 63) / 64, B_), 256, 0, stream>>>(
        out_t, (float*)d_out);
}

// Round 4
// 210.540 us; speedup vs baseline: 1.2445x; 1.2445x over previous
//
#include <hip/hip_runtime.h>
#include <math.h>

#define B_ 2
#define N_ 20000
#define C_ 64
#define K_ 16
#define CS_ 16
#define EPS_ 1e-5f

// bf16 round-to-nearest-even helpers
__device__ __forceinline__ unsigned int bfbits(float f)
{
    unsigned int b = __builtin_bit_cast(unsigned int, f);
    return (b + 0x7FFFu + ((b >> 16) & 1u)) >> 16;
}
__device__ __forceinline__ float bf_lo(unsigned int w)   // low 16 bits -> float
{
    return __builtin_bit_cast(float, w << 16);
}
__device__ __forceinline__ float bf_hi(unsigned int w)   // high 16 bits -> float
{
    return __builtin_bit_cast(float, w & 0xFFFF0000u);
}

// ---------------------------------------------------------------------------
// Kernel A: 1x1 conv projections, tiled mini-GEMM.
// Writes xq_t as f32 [pt][64] and kv_t as packed bf16 [pt][64] uints where
// uint c = bf16(xk[c]) | bf16(xv[c])<<16  -> one 256B row serves both gathers.
// ---------------------------------------------------------------------------
__device__ __forceinline__ void mv16(const float* __restrict__ W,
                                     const float* __restrict__ bias,
                                     int ob, const float (&x)[C_], float (&acc)[16])
{
#pragma unroll
    for (int jg = 0; jg < 4; jg++) {
        const float* r0 = W + (size_t)(ob + jg * 4) * C_;
        const float* r1 = r0 + C_;
        const float* r2 = r0 + 2 * C_;
        const float* r3 = r0 + 3 * C_;
        float a0 = bias[ob + jg * 4 + 0];
        float a1 = bias[ob + jg * 4 + 1];
        float a2 = bias[ob + jg * 4 + 2];
        float a3 = bias[ob + jg * 4 + 3];
#pragma unroll
        for (int ci = 0; ci < C_; ci++) {
            float xc = x[ci];
            a0 = fmaf(r0[ci], xc, a0);
            a1 = fmaf(r1[ci], xc, a1);
            a2 = fmaf(r2[ci], xc, a2);
            a3 = fmaf(r3[ci], xc, a3);
        }
        acc[jg * 4 + 0] = a0; acc[jg * 4 + 1] = a1;
        acc[jg * 4 + 2] = a2; acc[jg * 4 + 3] = a3;
    }
}

__global__ __launch_bounds__(256) void proj_kernel(
    const float* __restrict__ q, const float* __restrict__ kin,
    const float* __restrict__ wq, const float* __restrict__ bq,
    const float* __restrict__ wk, const float* __restrict__ bk,
    const float* __restrict__ wv, const float* __restrict__ bv,
    float* __restrict__ xq_t, unsigned int* __restrict__ kv_t)
{
    __shared__ float tin[C_][65];
    __shared__ float tout[C_][65];
    unsigned int* tout_u = reinterpret_cast<unsigned int*>(&tout[0][0]);

    const int t      = threadIdx.x;
    const int lane_p = t & 63;
    const int pt0    = blockIdx.x * 64;
    const int pt     = pt0 + lane_p;
    const int b      = pt / N_;
    const int n      = pt - b * N_;
    const size_t cbase = (size_t)b * C_ * N_ + n;

    const int oq = __builtin_amdgcn_readfirstlane(t >> 6);
    const int ob = oq * 16;

    const int s_p  = t >> 2;          // point within tile for store phase
    const int s_c0 = (t & 3) * 16;    // 16-channel chunk

    // ---- Q tile -> accq (xq), accv (xv) ----
#pragma unroll
    for (int r = 0; r < 16; r++) {
        int ci = ob + r;
        tin[ci][lane_p] = q[cbase + (size_t)ci * N_];
    }
    __syncthreads();

    float x[C_];
#pragma unroll
    for (int ci = 0; ci < C_; ci++) x[ci] = tin[ci][lane_p];

    float accq[16], accv[16];
    mv16(wq, bq, ob, x, accq);
    mv16(wv, bv, ob, x, accv);

    // stage + store xq (f32)
#pragma unroll
    for (int j = 0; j < 16; j++) tout[ob + j][lane_p] = accq[j];
    __syncthreads();
    {
        float4* dp = reinterpret_cast<float4*>(xq_t + (size_t)(pt0 + s_p) * C_ + s_c0);
#pragma unroll
        for (int j4 = 0; j4 < 4; j4++) {
            float4 v;
            v.x = tout[s_c0 + j4 * 4 + 0][s_p];
            v.y = tout[s_c0 + j4 * 4 + 1][s_p];
            v.z = tout[s_c0 + j4 * 4 + 2][s_p];
            v.w = tout[s_c0 + j4 * 4 + 3][s_p];
            dp[j4] = v;
        }
    }
    __syncthreads();   // all tout reads done

    // stage accv as bf16 in high half of tout_u; load K tile meanwhile
#pragma unroll
    for (int j = 0; j < 16; j++)
        tout_u[(ob + j) * 65 + lane_p] = bfbits(accv[j]) << 16;

#pragma unroll
    for (int r = 0; r < 16; r++) {
        int ci = ob + r;
        tin[ci][lane_p] = kin[cbase + (size_t)ci * N_];
    }
    __syncthreads();   // tin ready, tout_u(v) written
#pragma unroll
    for (int ci = 0; ci < C_; ci++) x[ci] = tin[ci][lane_p];

    float acck[16];
    mv16(wk, bk, ob, x, acck);
#pragma unroll
    for (int j = 0; j < 16; j++)
        tout_u[(ob + j) * 65 + lane_p] |= bfbits(acck[j]);   // same-lane RMW
    __syncthreads();

    // read out packed rows, coalesced uint4 stores (256B per point)
    {
        uint4* dp = reinterpret_cast<uint4*>(kv_t + (size_t)(pt0 + s_p) * C_ + s_c0);
#pragma unroll
        for (int j4 = 0; j4 < 4; j4++) {
            uint4 v;
            v.x = tout_u[(s_c0 + j4 * 4 + 0) * 65 + s_p];
            v.y = tout_u[(s_c0 + j4 * 4 + 1) * 65 + s_p];
            v.z = tout_u[(s_c0 + j4 * 4 + 2) * 65 + s_p];
            v.w = tout_u[(s_c0 + j4 * 4 + 3) * 65 + s_p];
            dp[j4] = v;
        }
    }
}

// ---------------------------------------------------------------------------
// Kernel B: per-point attention. 4 points per 256-thread block, one wave per
// point, wave-private LDS, no __syncthreads.
// XCD-aware batch partition: blocks dispatch round-robin over 8 XCDs;
// blockIdx%8 in {0..3} -> batch 0, {4..7} -> batch 1, so each XCD's gather
// working set is ONE batch's 5.12MB packed-bf16 kv rows (~fits its 4MB L2).
// ---------------------------------------------------------------------------
__device__ __forceinline__ void wave_fence()
{
    __builtin_amdgcn_wave_barrier();
}

__global__ __launch_bounds__(256, 7) void attn_kernel(
    const float* __restrict__ coord, const int* __restrict__ nbr,
    const float* __restrict__ xq_t, const unsigned int* __restrict__ kv_t,
    const float* __restrict__ p1_w, const float* __restrict__ p1_b,
    const float* __restrict__ p_bn_g, const float* __restrict__ p_bn_b,
    const float* __restrict__ p_bn_m, const float* __restrict__ p_bn_v,
    const float* __restrict__ p2_w, const float* __restrict__ p2_b,
    const float* __restrict__ w_bn1_g, const float* __restrict__ w_bn1_b,
    const float* __restrict__ w_bn1_m, const float* __restrict__ w_bn1_v,
    const float* __restrict__ w1_w, const float* __restrict__ w1_b,
    const float* __restrict__ w_bn2_g, const float* __restrict__ w_bn2_b,
    const float* __restrict__ w_bn2_m, const float* __restrict__ w_bn2_v,
    const float* __restrict__ w2_w, const float* __restrict__ w2_b,
    float* __restrict__ out_t)
{
    constexpr int WS = 68;                    // wbuf row stride (16B-aligned)
    constexpr int ZS = 17;
    constexpr int PW = K_ * WS + K_ * ZS;     // 1360 floats per wave slice
    __shared__ float lds[4 * PW];             // 21760 B -> 7 blocks/CU

    const int w  = __builtin_amdgcn_readfirstlane(threadIdx.x >> 6);
    const int c  = threadIdx.x & 63;

    // XCD-batch mapping: grid = 10000 blocks, %8 round-robin over XCDs
    const int i  = blockIdx.x;
    const int r  = i & 7;
    const int j  = i >> 3;                    // 0..1249
    const int b  = r >> 2;                    // batch
    const int chunk = (r & 3) * 1250 + j;     // 0..4999 within batch
    const int bn = b * N_ + chunk * 4 + w;    // this wave's point
    const int bB = b * N_;

    float* wbuf = lds + w * PW;
    float* zs   = wbuf + K_ * WS;

    // per-lane constants, BN affine folded
    float xq   = xq_t[(size_t)bn * C_ + c];
    float p2w0 = p2_w[c * 3 + 0], p2w1 = p2_w[c * 3 + 1], p2w2 = p2_w[c * 3 + 2];
    float p2b  = p2_b[c];
    float bn1s = w_bn1_g[c] * rsqrtf(w_bn1_v[c] + EPS_);
    float bn1b = w_bn1_b[c] - w_bn1_m[c] * bn1s;

    float p1w[9], pbs[3], pbb[3];             // wave-uniform -> SGPRs
#pragma unroll
    for (int jj = 0; jj < 9; jj++) p1w[jj] = p1_w[jj];
#pragma unroll
    for (int jj = 0; jj < 3; jj++) {
        float s = p_bn_g[jj] * rsqrtf(p_bn_v[jj] + EPS_);
        pbs[jj] = s;
        pbb[jj] = (p1_b[jj] - p_bn_m[jj]) * s + p_bn_b[jj];
    }

    // ---- phase 1: batched gather (ONE dword per neighbor: bf16 xk|xv) ----
    const int* nb = nbr + (size_t)bn * K_;
    int idxs[K_];
#pragma unroll
    for (int kk = 0; kk < K_; kk++) idxs[kk] = nb[kk];    // uniform -> s_load

    unsigned int kvw[K_];
#pragma unroll
    for (int kk = 0; kk < K_; kk++) {
        size_t base = (size_t)(bB + idxs[kk]) * C_;
        kvw[kk] = kv_t[base + c];                         // coalesced 256B row
    }

    float vreg[K_];
#pragma unroll
    for (int kk = 0; kk < K_; kk++) {
        int src = bB + idxs[kk];
        const float* cp = coord + (size_t)src * 3;        // uniform -> s_load
        float cx = cp[0], cy = cp[1], cz = cp[2];
        float h0 = fmaxf(0.f, (p1w[0]*cx + p1w[1]*cy + p1w[2]*cz) * pbs[0] + pbb[0]);
        float h1 = fmaxf(0.f, (p1w[3]*cx + p1w[4]*cy + p1w[5]*cz) * pbs[1] + pbb[1]);
        float h2 = fmaxf(0.f, (p1w[6]*cx + p1w[7]*cy + p1w[8]*cz) * pbs[2] + pbb[2]);
        float pr = fmaf(p2w0, h0, fmaf(p2w1, h1, fmaf(p2w2, h2, p2b)));
        float xk = bf_lo(kvw[kk]);
        float xv = bf_hi(kvw[kk]);
        wbuf[kk * WS + c] = fmaxf(0.f, (xk - xq + pr) * bn1s + bn1b);
        vreg[kk] = xv + pr;
    }
    wave_fence();

    // ---- phase 2a: u[g, k] = w1_w[g,:] . wbuf[k,:] ----
    const int g  = c & 15;
    const int kb = (c >> 4) * 4;
    float u0 = 0.f, u1 = 0.f, u2 = 0.f, u3 = 0.f;
    const float4* w1r = reinterpret_cast<const float4*>(w1_w + g * C_);
#pragma unroll
    for (int c4 = 0; c4 < 16; c4++) {
        float4 wr = w1r[c4];
        float4 b0 = *reinterpret_cast<const float4*>(&wbuf[(kb + 0) * WS + c4 * 4]);
        float4 b1 = *reinterpret_cast<const float4*>(&wbuf[(kb + 1) * WS + c4 * 4]);
        float4 b2 = *reinterpret_cast<const float4*>(&wbuf[(kb + 2) * WS + c4 * 4]);
        float4 b3 = *reinterpret_cast<const float4*>(&wbuf[(kb + 3) * WS + c4 * 4]);
        u0 = fmaf(wr.x, b0.x, u0); u0 = fmaf(wr.y, b0.y, u0); u0 = fmaf(wr.z, b0.z, u0); u0 = fmaf(wr.w, b0.w, u0);
        u1 = fmaf(wr.x, b1.x, u1); u1 = fmaf(wr.y, b1.y, u1); u1 = fmaf(wr.z, b1.z, u1); u1 = fmaf(wr.w, b1.w, u1);
        u2 = fmaf(wr.x, b2.x, u2); u2 = fmaf(wr.y, b2.y, u2); u2 = fmaf(wr.z, b2.z, u2); u2 = fmaf(wr.w, b2.w, u2);
        u3 = fmaf(wr.x, b3.x, u3); u3 = fmaf(wr.y, b3.y, u3); u3 = fmaf(wr.z, b3.z, u3); u3 = fmaf(wr.w, b3.w, u3);
    }
    float w1bb = w1_b[g];
    float bn2s = w_bn2_g[g] * rsqrtf(w_bn2_v[g] + EPS_);
    float bn2b = w_bn2_b[g] - w_bn2_m[g] * bn2s;
    zs[(kb + 0) * ZS + g] = fmaxf(0.f, (u0 + w1bb) * bn2s + bn2b);
    zs[(kb + 1) * ZS + g] = fmaxf(0.f, (u1 + w1bb) * bn2s + bn2b);
    zs[(kb + 2) * ZS + g] = fmaxf(0.f, (u2 + w1bb) * bn2s + bn2b);
    zs[(kb + 3) * ZS + g] = fmaxf(0.f, (u3 + w1bb) * bn2s + bn2b);
    wave_fence();

    // ---- phase 2b: t[g, k] = w2_b[g] + sum_gg w2_w[g,gg] * z[gg, k] ----
    float t0 = w2_b[g], t1 = t0, t2 = t0, t3 = t0;
#pragma unroll
    for (int gg = 0; gg < 16; gg++) {
        float w2 = w2_w[g * 16 + gg];
        t0 = fmaf(w2, zs[(kb + 0) * ZS + gg], t0);
        t1 = fmaf(w2, zs[(kb + 1) * ZS + gg], t1);
        t2 = fmaf(w2, zs[(kb + 2) * ZS + gg], t2);
        t3 = fmaf(w2, zs[(kb + 3) * ZS + gg], t3);
    }
    wave_fence();   // z reads issued before softmax overwrites zs

    // softmax over the 16 k's: 4 local + lanes {g, g+16, g+32, g+48}
    float m = fmaxf(fmaxf(t0, t1), fmaxf(t2, t3));
    m = fmaxf(m, __shfl_xor(m, 16));
    m = fmaxf(m, __shfl_xor(m, 32));
    float e0 = expf(t0 - m), e1 = expf(t1 - m), e2 = expf(t2 - m), e3 = expf(t3 - m);
    float s = e0 + e1 + e2 + e3;
    s += __shfl_xor(s, 16);
    s += __shfl_xor(s, 32);
    float inv = 1.0f / s;
    zs[(kb + 0) * ZS + g] = e0 * inv;
    zs[(kb + 1) * ZS + g] = e1 * inv;
    zs[(kb + 2) * ZS + g] = e2 * inv;
    zs[(kb + 3) * ZS + g] = e3 * inv;
    wave_fence();

    // ---- phase 3: out[c] = sum_k vreg[k] * soft[k][c & 15] ----
    float acc = 0.f;
#pragma unroll
    for (int kk = 0; kk < K_; kk++)
        acc = fmaf(vreg[kk], zs[kk * ZS + g], acc);
    out_t[(size_t)bn * C_ + c] = acc;
}

// ---------------------------------------------------------------------------
// Kernel C: transpose [B, N, C] -> [B, C, N], 64x64 LDS tiles.
// ---------------------------------------------------------------------------
__global__ __launch_bounds__(256) void transpose_kernel(const float* __restrict__ src,
                                                        float* __restrict__ dst)
{
    __shared__ float tile[64][65];
    int b  = blockIdx.y;
    int n0 = blockIdx.x * 64;
    int t  = threadIdx.x;

    int p  = t >> 2;
    int c0 = (t & 3) * 16;
    int n  = n0 + p;
    if (n < N_) {
        const float4* s = reinterpret_cast<const float4*>(src + ((size_t)b * N_ + n) * C_ + c0);
#pragma unroll
        for (int j = 0; j < 4; j++) {
            float4 v = s[j];
            tile[p][c0 + j * 4 + 0] = v.x;
            tile[p][c0 + j * 4 + 1] = v.y;
            tile[p][c0 + j * 4 + 2] = v.z;
            tile[p][c0 + j * 4 + 3] = v.w;
        }
    }
    __syncthreads();

    int n_off = t & 63;
    int cg    = t >> 6;
    if (n0 + n_off < N_) {
#pragma unroll
        for (int j = 0; j < 16; j++) {
            int cc = cg * 16 + j;
            dst[(size_t)b * C_ * N_ + (size_t)cc * N_ + n0 + n_off] = tile[n_off][cc];
        }
    }
}

// ---------------------------------------------------------------------------
extern "C" void kernel_launch(void* const* d_in, const int* in_sizes, int n_in,
                              void* d_out, int out_size, void* d_ws, size_t ws_size,
                              hipStream_t stream)
{
    const float* coord = (const float*)d_in[0];
    const float* q     = (const float*)d_in[1];
    const float* k     = (const float*)d_in[2];
    const int*   nbr   = (const int*)d_in[3];
    const float* wq = (const float*)d_in[4];
    const float* bq = (const float*)d_in[5];
    const float* wk = (const float*)d_in[6];
    const float* bk = (const float*)d_in[7];
    const float* wv = (const float*)d_in[8];
    const float* bv = (const float*)d_in[9];
    const float* p1_w = (const float*)d_in[10];
    const float* p1_b = (const float*)d_in[11];
    const float* p_bn_g = (const float*)d_in[12];
    const float* p_bn_b = (const float*)d_in[13];
    const float* p_bn_m = (const float*)d_in[14];
    const float* p_bn_v = (const float*)d_in[15];
    const float* p2_w = (const float*)d_in[16];
    const float* p2_b = (const float*)d_in[17];
    const float* w_bn1_g = (const float*)d_in[18];
    const float* w_bn1_b = (const float*)d_in[19];
    const float* w_bn1_m = (const float*)d_in[20];
    const float* w_bn1_v = (const float*)d_in[21];
    const float* w1_w = (const float*)d_in[22];
    const float* w1_b = (const float*)d_in[23];
    const float* w_bn2_g = (const float*)d_in[24];
    const float* w_bn2_b = (const float*)d_in[25];
    const float* w_bn2_m = (const float*)d_in[26];
    const float* w_bn2_v = (const float*)d_in[27];
    const float* w2_w = (const float*)d_in[28];
    const float* w2_b = (const float*)d_in[29];

    const size_t PTS = (size_t)B_ * N_;        // 40000
    float* ws   = (float*)d_ws;
    float* xq_t = ws;                                  // [PTS][64] f32
    unsigned int* kv_t = (unsigned int*)(ws + PTS * C_); // [PTS][64] packed bf16
    float* out_t = xq_t;  // safe alias: wave bn reads xq_t[bn] before writing out_t[bn]

    proj_kernel<<<(B_ * N_) / 64, 256, 0, stream>>>(
        q, k, wq, bq, wk, bk, wv, bv, xq_t, kv_t);

    attn_kernel<<<(B_ * N_) / 4, 256, 0, stream>>>(
        coord, nbr, xq_t, kv_t,
        p1_w, p1_b, p_bn_g, p_bn_b, p_bn_m, p_bn_v, p2_w, p2_b,
        w_bn1_g, w_bn1_b, w_bn1_m, w_bn1_v, w1_w, w1_b,
        w_bn2_g, w_bn2_b, w_bn2_m, w_bn2_v, w2_w, w2_b,
        out_t);

    transpose_kernel<<<dim3((N_ + 63) / 64, B_), 256, 0, stream>>>(
        out_t, (float*)d_out);
}

// Round 5
// 92.831 us; speedup vs baseline: 2.8225x; 2.2680x over previous
//
#include <hip/hip_runtime.h>
#include <math.h>

#define B_ 2
#define N_ 20000
#define C_ 64
#define K_ 16
#define CS_ 16
#define EPS_ 1e-5f

typedef float f32x4_t  __attribute__((ext_vector_type(4)));
typedef short bf16x8_t __attribute__((ext_vector_type(8)));
typedef short bf16x4_t __attribute__((ext_vector_type(4)));

// bf16 round-to-nearest-even helpers
__device__ __forceinline__ unsigned int bfbits(float f)
{
    unsigned int b = __builtin_bit_cast(unsigned int, f);
    return (b + 0x7FFFu + ((b >> 16) & 1u)) >> 16;
}
__device__ __forceinline__ float bf_lo(unsigned int w)
{
    return __builtin_bit_cast(float, w << 16);
}
__device__ __forceinline__ float bf_hi(unsigned int w)
{
    return __builtin_bit_cast(float, w & 0xFFFF0000u);
}

// ---------------------------------------------------------------------------
// Kernel A: projections + positional MLP fused.
// pos[c] = p2_w[c,:] @ relu(bn_p(p1_w @ coord)) + p2_b  depends only on the
// SOURCE point, so it is computed here once and folded into the packed row:
//   kv_t[pt][c] = bf16(xk[c]+pos[c]) | bf16(xv[c]+pos[c]) << 16
// xq_t stays f32 (center-side, never gathered).
// ---------------------------------------------------------------------------
__device__ __forceinline__ void mv16(const float* __restrict__ W,
                                     const float* __restrict__ bias,
                                     int ob, const float (&x)[C_], float (&acc)[16])
{
#pragma unroll
    for (int jg = 0; jg < 4; jg++) {
        const float* r0 = W + (size_t)(ob + jg * 4) * C_;
        const float* r1 = r0 + C_;
        const float* r2 = r0 + 2 * C_;
        const float* r3 = r0 + 3 * C_;
        float a0 = bias[ob + jg * 4 + 0];
        float a1 = bias[ob + jg * 4 + 1];
        float a2 = bias[ob + jg * 4 + 2];
        float a3 = bias[ob + jg * 4 + 3];
#pragma unroll
        for (int ci = 0; ci < C_; ci++) {
            float xc = x[ci];
            a0 = fmaf(r0[ci], xc, a0);
            a1 = fmaf(r1[ci], xc, a1);
            a2 = fmaf(r2[ci], xc, a2);
            a3 = fmaf(r3[ci], xc, a3);
        }
        acc[jg * 4 + 0] = a0; acc[jg * 4 + 1] = a1;
        acc[jg * 4 + 2] = a2; acc[jg * 4 + 3] = a3;
    }
}

__global__ __launch_bounds__(256) void proj_kernel(
    const float* __restrict__ q, const float* __restrict__ kin,
    const float* __restrict__ coord,
    const float* __restrict__ wq, const float* __restrict__ bq,
    const float* __restrict__ wk, const float* __restrict__ bk,
    const float* __restrict__ wv, const float* __restrict__ bv,
    const float* __restrict__ p1_w, const float* __restrict__ p1_b,
    const float* __restrict__ p_bn_g, const float* __restrict__ p_bn_b,
    const float* __restrict__ p_bn_m, const float* __restrict__ p_bn_v,
    const float* __restrict__ p2_w, const float* __restrict__ p2_b,
    float* __restrict__ xq_t, unsigned int* __restrict__ kv_t)
{
    __shared__ float tin[C_][65];
    __shared__ float tout[C_][65];
    unsigned int* tout_u = reinterpret_cast<unsigned int*>(&tout[0][0]);

    const int t      = threadIdx.x;
    const int lane_p = t & 63;
    const int pt0    = blockIdx.x * 64;
    const int pt     = pt0 + lane_p;
    const int b      = pt / N_;
    const int n      = pt - b * N_;
    const size_t cbase = (size_t)b * C_ * N_ + n;

    const int oq = __builtin_amdgcn_readfirstlane(t >> 6);
    const int ob = oq * 16;

    const int s_p  = t >> 2;
    const int s_c0 = (t & 3) * 16;

    // ---- positional MLP for this (point, channel-block) ----
    float pbs[3], pbb[3];
#pragma unroll
    for (int j = 0; j < 3; j++) {
        float s = p_bn_g[j] * rsqrtf(p_bn_v[j] + EPS_);
        pbs[j] = s;
        pbb[j] = (p1_b[j] - p_bn_m[j]) * s + p_bn_b[j];
    }
    float cx = coord[pt * 3 + 0], cy = coord[pt * 3 + 1], cz = coord[pt * 3 + 2];
    float h0 = fmaxf(0.f, (p1_w[0]*cx + p1_w[1]*cy + p1_w[2]*cz) * pbs[0] + pbb[0]);
    float h1 = fmaxf(0.f, (p1_w[3]*cx + p1_w[4]*cy + p1_w[5]*cz) * pbs[1] + pbb[1]);
    float h2 = fmaxf(0.f, (p1_w[6]*cx + p1_w[7]*cy + p1_w[8]*cz) * pbs[2] + pbb[2]);
    float pr[16];
#pragma unroll
    for (int j = 0; j < 16; j++) {
        int ch = ob + j;                       // wave-uniform -> s_loads
        pr[j] = fmaf(p2_w[ch*3+0], h0, fmaf(p2_w[ch*3+1], h1,
                fmaf(p2_w[ch*3+2], h2, p2_b[ch])));
    }

    // ---- Q tile -> accq (xq), accv (xv) ----
#pragma unroll
    for (int r = 0; r < 16; r++) {
        int ci = ob + r;
        tin[ci][lane_p] = q[cbase + (size_t)ci * N_];
    }
    __syncthreads();

    float x[C_];
#pragma unroll
    for (int ci = 0; ci < C_; ci++) x[ci] = tin[ci][lane_p];

    float accq[16], accv[16];
    mv16(wq, bq, ob, x, accq);
    mv16(wv, bv, ob, x, accv);

    // stage + store xq (f32)
#pragma unroll
    for (int j = 0; j < 16; j++) tout[ob + j][lane_p] = accq[j];
    __syncthreads();
    {
        float4* dp = reinterpret_cast<float4*>(xq_t + (size_t)(pt0 + s_p) * C_ + s_c0);
#pragma unroll
        for (int j4 = 0; j4 < 4; j4++) {
            float4 v;
            v.x = tout[s_c0 + j4 * 4 + 0][s_p];
            v.y = tout[s_c0 + j4 * 4 + 1][s_p];
            v.z = tout[s_c0 + j4 * 4 + 2][s_p];
            v.w = tout[s_c0 + j4 * 4 + 3][s_p];
            dp[j4] = v;
        }
    }
    __syncthreads();

    // stage xv+pos as bf16 hi-halves; load K tile meanwhile
#pragma unroll
    for (int j = 0; j < 16; j++)
        tout_u[(ob + j) * 65 + lane_p] = bfbits(accv[j] + pr[j]) << 16;

#pragma unroll
    for (int r = 0; r < 16; r++) {
        int ci = ob + r;
        tin[ci][lane_p] = kin[cbase + (size_t)ci * N_];
    }
    __syncthreads();
#pragma unroll
    for (int ci = 0; ci < C_; ci++) x[ci] = tin[ci][lane_p];

    float acck[16];
    mv16(wk, bk, ob, x, acck);
#pragma unroll
    for (int j = 0; j < 16; j++)
        tout_u[(ob + j) * 65 + lane_p] |= bfbits(acck[j] + pr[j]);   // same-lane RMW
    __syncthreads();

    {
        uint4* dp = reinterpret_cast<uint4*>(kv_t + (size_t)(pt0 + s_p) * C_ + s_c0);
#pragma unroll
        for (int j4 = 0; j4 < 4; j4++) {
            uint4 v;
            v.x = tout_u[(s_c0 + j4 * 4 + 0) * 65 + s_p];
            v.y = tout_u[(s_c0 + j4 * 4 + 1) * 65 + s_p];
            v.z = tout_u[(s_c0 + j4 * 4 + 2) * 65 + s_p];
            v.w = tout_u[(s_c0 + j4 * 4 + 3) * 65 + s_p];
            dp[j4] = v;
        }
    }
}

// ---------------------------------------------------------------------------
// Kernel B: attention via MFMA. 4 points / 256-thread block, one wave per
// point, wave-private LDS, no __syncthreads.
// Per point:
//   phase1: gather packed rows, w[k][c] = relu(bn1(kpr - xq)) -> bf16 LDS tile
//           (16 rows x 72 bf16, 144B stride -> conflict-free b128 reads)
//   phase2: u(16x16) = w1(16x64) @ w^T  via 2x mfma_f32_16x16x32_bf16
//           z = relu(bn2(u)) in regs; C-frag of u IS the B-frag of
//           t = w2 @ z via mfma_f32_16x16x16bf16_1k. Softmax over nbr =
//           16-lane-group shfl_xor sum (exp without max-sub: |t| << 80).
//   phase3: out[c] = sum_k v[k] * soft[c&15][k]  (v = hi half of packed row)
// ---------------------------------------------------------------------------
__device__ __forceinline__ void wave_fence()
{
    __builtin_amdgcn_wave_barrier();
}

__global__ __launch_bounds__(256, 5) void attn_kernel(
    const int* __restrict__ nbr,
    const float* __restrict__ xq_t, const unsigned int* __restrict__ kv_t,
    const float* __restrict__ w_bn1_g, const float* __restrict__ w_bn1_b,
    const float* __restrict__ w_bn1_m, const float* __restrict__ w_bn1_v,
    const float* __restrict__ w1_w, const float* __restrict__ w1_b,
    const float* __restrict__ w_bn2_g, const float* __restrict__ w_bn2_b,
    const float* __restrict__ w_bn2_m, const float* __restrict__ w_bn2_v,
    const float* __restrict__ w2_w, const float* __restrict__ w2_b,
    float* __restrict__ out_t)
{
    constexpr int WROW = 72;              // bf16 elems per w-tile row (144B)
    constexpr int WN   = K_ * WROW;       // 1152 ushort = 2304B per wave
    constexpr int SS   = 17;              // softmax buf row stride
    constexpr int SN   = K_ * SS;         // 272 f32 = 1088B per wave
    __shared__ unsigned short wlds_all[4 * WN];   // 9216B
    __shared__ float          sfb_all[4 * SN];    // 4352B

    const int w  = __builtin_amdgcn_readfirstlane(threadIdx.x >> 6);
    const int l  = threadIdx.x & 63;
    const int al = l & 15;                // A-row / B-col / neighbor-col role
    const int qd = l >> 4;                // k-chunk quad

    // XCD-batch mapping (as R4): blockIdx%8 round-robins XCDs
    const int i  = blockIdx.x;
    const int r  = i & 7;
    const int j  = i >> 3;
    const int b  = r >> 2;
    const int chunk = (r & 3) * 1250 + j;
    const int bn = b * N_ + chunk * 4 + w;
    const int bB = b * N_;

    unsigned short* wlds = wlds_all + w * WN;
    float*          sfb  = sfb_all + w * SN;

    // ---- per-lane constants ----
    float xq   = xq_t[(size_t)bn * C_ + l];
    float bn1s = w_bn1_g[l] * rsqrtf(w_bn1_v[l] + EPS_);
    float bn1b = w_bn1_b[l] - w_bn1_m[l] * bn1s;

    // A-frag w1 (16x32 per half): lane holds w1_w[al][8*qd + i + 32*half]
    union { bf16x8_t v; unsigned int u[4]; } a1[2];
#pragma unroll
    for (int half = 0; half < 2; half++) {
        const float4 f0 = *reinterpret_cast<const float4*>(w1_w + al * C_ + half * 32 + qd * 8);
        const float4 f1 = *reinterpret_cast<const float4*>(w1_w + al * C_ + half * 32 + qd * 8 + 4);
        a1[half].u[0] = bfbits(f0.x) | (bfbits(f0.y) << 16);
        a1[half].u[1] = bfbits(f0.z) | (bfbits(f0.w) << 16);
        a1[half].u[2] = bfbits(f1.x) | (bfbits(f1.y) << 16);
        a1[half].u[3] = bfbits(f1.z) | (bfbits(f1.w) << 16);
    }
    // A-frag w2 (16x16): lane holds w2_w[al][4*qd + i]
    union { bf16x4_t v; unsigned int u[2]; } a2;
    {
        const float4 f = *reinterpret_cast<const float4*>(w2_w + al * 16 + qd * 4);
        a2.u[0] = bfbits(f.x) | (bfbits(f.y) << 16);
        a2.u[1] = bfbits(f.z) | (bfbits(f.w) << 16);
    }
    // C-frag row constants (rows 4*qd + reg): bn2/w1_b folded, w2_b
    float zsc[4], zbi[4], tbi[4];
    {
        const float4 g2  = *reinterpret_cast<const float4*>(w_bn2_g + 4 * qd);
        const float4 bb2 = *reinterpret_cast<const float4*>(w_bn2_b + 4 * qd);
        const float4 m2  = *reinterpret_cast<const float4*>(w_bn2_m + 4 * qd);
        const float4 v2  = *reinterpret_cast<const float4*>(w_bn2_v + 4 * qd);
        const float4 ub  = *reinterpret_cast<const float4*>(w1_b + 4 * qd);
        const float4 tb  = *reinterpret_cast<const float4*>(w2_b + 4 * qd);
#pragma unroll
        for (int rr = 0; rr < 4; rr++) {
            float gg = (&g2.x)[rr], vv = (&v2.x)[rr];
            float s = gg * rsqrtf(vv + EPS_);
            zsc[rr] = s;
            zbi[rr] = ((&ub.x)[rr] - (&m2.x)[rr]) * s + (&bb2.x)[rr];  // (u+w1b-m)*s+b
            tbi[rr] = (&tb.x)[rr];
        }
    }

    // ---- phase 1: gather + build bf16 w-tile ----
    const int* nb = nbr + (size_t)bn * K_;
    int idxs[K_];
#pragma unroll
    for (int kk = 0; kk < K_; kk++) idxs[kk] = nb[kk];    // uniform -> s_load

    unsigned int kvw[K_];
#pragma unroll
    for (int kk = 0; kk < K_; kk++)
        kvw[kk] = kv_t[(size_t)(bB + idxs[kk]) * C_ + l]; // coalesced 256B rows

#pragma unroll
    for (int kk = 0; kk < K_; kk++) {
        float kpr = bf_lo(kvw[kk]);                       // xk + pos
        float wv_ = fmaxf(0.f, (kpr - xq) * bn1s + bn1b);
        wlds[kk * WROW + l] = (unsigned short)bfbits(wv_);
    }
    wave_fence();

    // ---- phase 2a: u = w1 @ w^T  (2x mfma 16x16x32) ----
    const bf16x8_t b0 = *reinterpret_cast<const bf16x8_t*>(wlds + al * WROW + qd * 8);
    const bf16x8_t b1 = *reinterpret_cast<const bf16x8_t*>(wlds + al * WROW + 32 + qd * 8);
    f32x4_t u = {0.f, 0.f, 0.f, 0.f};
    u = __builtin_amdgcn_mfma_f32_16x16x32_bf16(a1[0].v, b0, u, 0, 0, 0);
    u = __builtin_amdgcn_mfma_f32_16x16x32_bf16(a1[1].v, b1, u, 0, 0, 0);

    // z = relu(bn2(u + w1_b)) -> bf16 B-frag for phase 2b (no LDS round-trip)
    union { bf16x4_t v; unsigned int u2[2]; } zb;
    {
        float z0 = fmaxf(0.f, u[0] * zsc[0] + zbi[0]);
        float z1 = fmaxf(0.f, u[1] * zsc[1] + zbi[1]);
        float z2 = fmaxf(0.f, u[2] * zsc[2] + zbi[2]);
        float z3 = fmaxf(0.f, u[3] * zsc[3] + zbi[3]);
        zb.u2[0] = bfbits(z0) | (bfbits(z1) << 16);
        zb.u2[1] = bfbits(z2) | (bfbits(z3) << 16);
    }

    // ---- phase 2b: t = w2 @ z  (mfma 16x16x16) ----
    f32x4_t t4 = {0.f, 0.f, 0.f, 0.f};
    t4 = __builtin_amdgcn_mfma_f32_16x16x16bf16_1k(a2.v, zb.v, t4, 0, 0, 0);

    // ---- softmax over neighbors (cols) per row g = 4*qd+reg ----
    float e[4], sden[4];
#pragma unroll
    for (int rr = 0; rr < 4; rr++) {
        e[rr] = __expf(t4[rr] + tbi[rr]);      // no max-sub: |t| << 80
        float s = e[rr];
        s += __shfl_xor(s, 1);
        s += __shfl_xor(s, 2);
        s += __shfl_xor(s, 4);
        s += __shfl_xor(s, 8);
        sden[rr] = s;
    }
#pragma unroll
    for (int rr = 0; rr < 4; rr++)
        sfb[al * SS + 4 * qd + rr] = e[rr] * __builtin_amdgcn_rcpf(sden[rr]);
    wave_fence();

    // ---- phase 3: out[c] = sum_k v[k] * soft[c&15][k] ----
    float acc = 0.f;
#pragma unroll
    for (int kk = 0; kk < K_; kk++)
        acc = fmaf(bf_hi(kvw[kk]), sfb[kk * SS + al], acc);
    out_t[(size_t)bn * C_ + l] = acc;
}

// ---------------------------------------------------------------------------
// Kernel C: transpose [B, N, C] -> [B, C, N], 64x64 LDS tiles.
// ---------------------------------------------------------------------------
__global__ __launch_bounds__(256) void transpose_kernel(const float* __restrict__ src,
                                                        float* __restrict__ dst)
{
    __shared__ float tile[64][65];
    int b  = blockIdx.y;
    int n0 = blockIdx.x * 64;
    int t  = threadIdx.x;

    int p  = t >> 2;
    int c0 = (t & 3) * 16;
    int n  = n0 + p;
    if (n < N_) {
        const float4* s = reinterpret_cast<const float4*>(src + ((size_t)b * N_ + n) * C_ + c0);
#pragma unroll
        for (int j = 0; j < 4; j++) {
            float4 v = s[j];
            tile[p][c0 + j * 4 + 0] = v.x;
            tile[p][c0 + j * 4 + 1] = v.y;
            tile[p][c0 + j * 4 + 2] = v.z;
            tile[p][c0 + j * 4 + 3] = v.w;
        }
    }
    __syncthreads();

    int n_off = t & 63;
    int cg    = t >> 6;
    if (n0 + n_off < N_) {
#pragma unroll
        for (int j = 0; j < 16; j++) {
            int cc = cg * 16 + j;
            dst[(size_t)b * C_ * N_ + (size_t)cc * N_ + n0 + n_off] = tile[n_off][cc];
        }
    }
}

// ---------------------------------------------------------------------------
extern "C" void kernel_launch(void* const* d_in, const int* in_sizes, int n_in,
                              void* d_out, int out_size, void* d_ws, size_t ws_size,
                              hipStream_t stream)
{
    const float* coord = (const float*)d_in[0];
    const float* q     = (const float*)d_in[1];
    const float* k     = (const float*)d_in[2];
    const int*   nbr   = (const int*)d_in[3];
    const float* wq = (const float*)d_in[4];
    const float* bq = (const float*)d_in[5];
    const float* wk = (const float*)d_in[6];
    const float* bk = (const float*)d_in[7];
    const float* wv = (const float*)d_in[8];
    const float* bv = (const float*)d_in[9];
    const float* p1_w = (const float*)d_in[10];
    const float* p1_b = (const float*)d_in[11];
    const float* p_bn_g = (const float*)d_in[12];
    const float* p_bn_b = (const float*)d_in[13];
    const float* p_bn_m = (const float*)d_in[14];
    const float* p_bn_v = (const float*)d_in[15];
    const float* p2_w = (const float*)d_in[16];
    const float* p2_b = (const float*)d_in[17];
    const float* w_bn1_g = (const float*)d_in[18];
    const float* w_bn1_b = (const float*)d_in[19];
    const float* w_bn1_m = (const float*)d_in[20];
    const float* w_bn1_v = (const float*)d_in[21];
    const float* w1_w = (const float*)d_in[22];
    const float* w1_b = (const float*)d_in[23];
    const float* w_bn2_g = (const float*)d_in[24];
    const float* w_bn2_b = (const float*)d_in[25];
    const float* w_bn2_m = (const float*)d_in[26];
    const float* w_bn2_v = (const float*)d_in[27];
    const float* w2_w = (const float*)d_in[28];
    const float* w2_b = (const float*)d_in[29];

    const size_t PTS = (size_t)B_ * N_;        // 40000
    float* ws   = (float*)d_ws;
    float* xq_t = ws;                                    // [PTS][64] f32
    unsigned int* kv_t = (unsigned int*)(ws + PTS * C_); // [PTS][64] packed bf16 (k+pos | v+pos)
    float* out_t = xq_t;  // safe alias: wave bn reads xq_t[bn] before writing out_t[bn]

    proj_kernel<<<(B_ * N_) / 64, 256, 0, stream>>>(
        q, k, coord, wq, bq, wk, bk, wv, bv,
        p1_w, p1_b, p_bn_g, p_bn_b, p_bn_m, p_bn_v, p2_w, p2_b,
        xq_t, kv_t);

    attn_kernel<<<(B_ * N_) / 4, 256, 0, stream>>>(
        nbr, xq_t, kv_t,
        w_bn1_g, w_bn1_b, w_bn1_m, w_bn1_v, w1_w, w1_b,
        w_bn2_g, w_bn2_b, w_bn2_m, w_bn2_v, w2_w, w2_b,
        out_t);

    transpose_kernel<<<dim3((N_ + 63) / 64, B_), 256, 0, stream>>>(
        out_t, (float*)d_out);
}

// Round 6
// 74.610 us; speedup vs baseline: 3.5118x; 1.2442x over previous
//
#include <hip/hip_runtime.h>
#include <math.h>

#define B_ 2
#define N_ 20000
#define C_ 64
#define K_ 16
#define CS_ 16
#define EPS_ 1e-5f

typedef float f32x4_t  __attribute__((ext_vector_type(4)));
typedef short bf16x8_t __attribute__((ext_vector_type(8)));
typedef short bf16x4_t __attribute__((ext_vector_type(4)));

// bf16 round-to-nearest-even helpers
__device__ __forceinline__ unsigned int bfbits(float f)
{
    unsigned int b = __builtin_bit_cast(unsigned int, f);
    return (b + 0x7FFFu + ((b >> 16) & 1u)) >> 16;
}
__device__ __forceinline__ float bf_lo(unsigned int w)
{
    return __builtin_bit_cast(float, w << 16);
}
__device__ __forceinline__ float bf_hi(unsigned int w)
{
    return __builtin_bit_cast(float, w & 0xFFFF0000u);
}

// ---------------------------------------------------------------------------
// Kernel A: projections + positional MLP, MFMA, zero LDS / zero barriers.
// Block = 256 thr = 4 waves; block owns 16 points, wave w owns out-channel
// group og=w (16 channels). B-frags (input columns) are loaded straight from
// global [C][N] layout (lanes of equal qd read 16 consecutive points ->
// 4x64B segments per load instr), converted bf16 in regs. 6 MFMAs per wave
// (xq, xv share the q B-frag). C-frag rows are 4 consecutive channels ->
// float4 / uint4 stores.
//   xq_t[pt][c] (f32)  and  kv_t[pt][c] = bf16(xk+pos) | bf16(xv+pos)<<16
// Fragment mappings identical to the ones already correctness-verified in
// attn_kernel (A: row=l&15, k=(l>>4)*8+i; C: col=l&15, row=(l>>4)*4+reg).
// ---------------------------------------------------------------------------
__global__ __launch_bounds__(256) void proj_kernel(
    const float* __restrict__ q, const float* __restrict__ kin,
    const float* __restrict__ coord,
    const float* __restrict__ wq, const float* __restrict__ bq,
    const float* __restrict__ wk, const float* __restrict__ bk,
    const float* __restrict__ wv, const float* __restrict__ bv,
    const float* __restrict__ p1_w, const float* __restrict__ p1_b,
    const float* __restrict__ p_bn_g, const float* __restrict__ p_bn_b,
    const float* __restrict__ p_bn_m, const float* __restrict__ p_bn_v,
    const float* __restrict__ p2_w, const float* __restrict__ p2_b,
    float* __restrict__ xq_t, unsigned int* __restrict__ kv_t)
{
    const int t   = threadIdx.x;
    const int og  = __builtin_amdgcn_readfirstlane(t >> 6);  // wave's channel group
    const int l   = t & 63;
    const int col = l & 15;          // point within 16-pt group (B col / C col)
    const int qd  = l >> 4;          // k-chunk / C row-quad
    const int pt0 = blockIdx.x * 16; // 2500 blocks; batch boundary 20000%16==0
    const int pt  = pt0 + col;
    const int b   = pt0 / N_;        // uniform within block (no straddle)
    const int n   = pt - b * N_;
    const size_t cbase = (size_t)b * C_ * N_ + n;

    // ---- B-fragments from global, bf16-packed in regs ----
    union bf8u { bf16x8_t v; unsigned int u[4]; };
    bf8u bq_[2], bk_[2];
#pragma unroll
    for (int half = 0; half < 2; half++) {
#pragma unroll
        for (int i2 = 0; i2 < 4; i2++) {
            int ci = half * 32 + qd * 8 + i2 * 2;
            float q0 = q[cbase + (size_t)ci * N_];
            float q1 = q[cbase + (size_t)(ci + 1) * N_];
            float k0 = kin[cbase + (size_t)ci * N_];
            float k1 = kin[cbase + (size_t)(ci + 1) * N_];
            bq_[half].u[i2] = bfbits(q0) | (bfbits(q1) << 16);
            bk_[half].u[i2] = bfbits(k0) | (bfbits(k1) << 16);
        }
    }

    // ---- A-fragments (weight rows, row = og*16+col) ----
    const int arow = og * 16 + col;
    bf8u awq[2], awk[2], awv[2];
#pragma unroll
    for (int half = 0; half < 2; half++) {
        const float4 fq0 = *reinterpret_cast<const float4*>(wq + (size_t)arow * C_ + half * 32 + qd * 8);
        const float4 fq1 = *reinterpret_cast<const float4*>(wq + (size_t)arow * C_ + half * 32 + qd * 8 + 4);
        const float4 fk0 = *reinterpret_cast<const float4*>(wk + (size_t)arow * C_ + half * 32 + qd * 8);
        const float4 fk1 = *reinterpret_cast<const float4*>(wk + (size_t)arow * C_ + half * 32 + qd * 8 + 4);
        const float4 fv0 = *reinterpret_cast<const float4*>(wv + (size_t)arow * C_ + half * 32 + qd * 8);
        const float4 fv1 = *reinterpret_cast<const float4*>(wv + (size_t)arow * C_ + half * 32 + qd * 8 + 4);
        awq[half].u[0] = bfbits(fq0.x) | (bfbits(fq0.y) << 16);
        awq[half].u[1] = bfbits(fq0.z) | (bfbits(fq0.w) << 16);
        awq[half].u[2] = bfbits(fq1.x) | (bfbits(fq1.y) << 16);
        awq[half].u[3] = bfbits(fq1.z) | (bfbits(fq1.w) << 16);
        awk[half].u[0] = bfbits(fk0.x) | (bfbits(fk0.y) << 16);
        awk[half].u[1] = bfbits(fk0.z) | (bfbits(fk0.w) << 16);
        awk[half].u[2] = bfbits(fk1.x) | (bfbits(fk1.y) << 16);
        awk[half].u[3] = bfbits(fk1.z) | (bfbits(fk1.w) << 16);
        awv[half].u[0] = bfbits(fv0.x) | (bfbits(fv0.y) << 16);
        awv[half].u[1] = bfbits(fv0.z) | (bfbits(fv0.w) << 16);
        awv[half].u[2] = bfbits(fv1.x) | (bfbits(fv1.y) << 16);
        awv[half].u[3] = bfbits(fv1.z) | (bfbits(fv1.w) << 16);
    }

    // ---- MFMAs ----
    f32x4_t uq = {0.f, 0.f, 0.f, 0.f};
    f32x4_t uv = {0.f, 0.f, 0.f, 0.f};
    f32x4_t uk = {0.f, 0.f, 0.f, 0.f};
    uq = __builtin_amdgcn_mfma_f32_16x16x32_bf16(awq[0].v, bq_[0].v, uq, 0, 0, 0);
    uq = __builtin_amdgcn_mfma_f32_16x16x32_bf16(awq[1].v, bq_[1].v, uq, 0, 0, 0);
    uv = __builtin_amdgcn_mfma_f32_16x16x32_bf16(awv[0].v, bq_[0].v, uv, 0, 0, 0);
    uv = __builtin_amdgcn_mfma_f32_16x16x32_bf16(awv[1].v, bq_[1].v, uv, 0, 0, 0);
    uk = __builtin_amdgcn_mfma_f32_16x16x32_bf16(awk[0].v, bk_[0].v, uk, 0, 0, 0);
    uk = __builtin_amdgcn_mfma_f32_16x16x32_bf16(awk[1].v, bk_[1].v, uk, 0, 0, 0);

    // ---- positional MLP for the lane's point, 4 channels qd*4+rr ----
    float pbs[3], pbb[3];
#pragma unroll
    for (int j = 0; j < 3; j++) {
        float s = p_bn_g[j] * rsqrtf(p_bn_v[j] + EPS_);
        pbs[j] = s;
        pbb[j] = (p1_b[j] - p_bn_m[j]) * s + p_bn_b[j];
    }
    float cx = coord[pt * 3 + 0], cy = coord[pt * 3 + 1], cz = coord[pt * 3 + 2];
    float h0 = fmaxf(0.f, (p1_w[0]*cx + p1_w[1]*cy + p1_w[2]*cz) * pbs[0] + pbb[0]);
    float h1 = fmaxf(0.f, (p1_w[3]*cx + p1_w[4]*cy + p1_w[5]*cz) * pbs[1] + pbb[1]);
    float h2 = fmaxf(0.f, (p1_w[6]*cx + p1_w[7]*cy + p1_w[8]*cz) * pbs[2] + pbb[2]);

    const int ch0 = og * 16 + qd * 4;
    float pos[4];
#pragma unroll
    for (int rr = 0; rr < 4; rr++) {
        int ch = ch0 + rr;
        pos[rr] = fmaf(p2_w[ch*3+0], h0, fmaf(p2_w[ch*3+1], h1,
                  fmaf(p2_w[ch*3+2], h2, p2_b[ch])));
    }

    // ---- epilogue: biases + stores ----
    const float4 bqv = *reinterpret_cast<const float4*>(bq + ch0);
    const float4 bkv = *reinterpret_cast<const float4*>(bk + ch0);
    const float4 bvv = *reinterpret_cast<const float4*>(bv + ch0);

    float4 xqo;
    xqo.x = uq[0] + bqv.x; xqo.y = uq[1] + bqv.y;
    xqo.z = uq[2] + bqv.z; xqo.w = uq[3] + bqv.w;
    *reinterpret_cast<float4*>(xq_t + (size_t)pt * C_ + ch0) = xqo;

    uint4 kvo;
#pragma unroll
    for (int rr = 0; rr < 4; rr++) {
        float kk = uk[rr] + (&bkv.x)[rr] + pos[rr];
        float vv = uv[rr] + (&bvv.x)[rr] + pos[rr];
        (&kvo.x)[rr] = bfbits(kk) | (bfbits(vv) << 16);
    }
    *reinterpret_cast<uint4*>(kv_t + (size_t)pt * C_ + ch0) = kvo;
}

// ---------------------------------------------------------------------------
// Kernel B: attention via MFMA (unchanged from R5).
// ---------------------------------------------------------------------------
__device__ __forceinline__ void wave_fence()
{
    __builtin_amdgcn_wave_barrier();
}

__global__ __launch_bounds__(256, 5) void attn_kernel(
    const int* __restrict__ nbr,
    const float* __restrict__ xq_t, const unsigned int* __restrict__ kv_t,
    const float* __restrict__ w_bn1_g, const float* __restrict__ w_bn1_b,
    const float* __restrict__ w_bn1_m, const float* __restrict__ w_bn1_v,
    const float* __restrict__ w1_w, const float* __restrict__ w1_b,
    const float* __restrict__ w_bn2_g, const float* __restrict__ w_bn2_b,
    const float* __restrict__ w_bn2_m, const float* __restrict__ w_bn2_v,
    const float* __restrict__ w2_w, const float* __restrict__ w2_b,
    float* __restrict__ out_t)
{
    constexpr int WROW = 72;
    constexpr int WN   = K_ * WROW;
    constexpr int SS   = 17;
    constexpr int SN   = K_ * SS;
    __shared__ unsigned short wlds_all[4 * WN];
    __shared__ float          sfb_all[4 * SN];

    const int w  = __builtin_amdgcn_readfirstlane(threadIdx.x >> 6);
    const int l  = threadIdx.x & 63;
    const int al = l & 15;
    const int qd = l >> 4;

    const int i  = blockIdx.x;
    const int r  = i & 7;
    const int j  = i >> 3;
    const int b  = r >> 2;
    const int chunk = (r & 3) * 1250 + j;
    const int bn = b * N_ + chunk * 4 + w;
    const int bB = b * N_;

    unsigned short* wlds = wlds_all + w * WN;
    float*          sfb  = sfb_all + w * SN;

    float xq   = xq_t[(size_t)bn * C_ + l];
    float bn1s = w_bn1_g[l] * rsqrtf(w_bn1_v[l] + EPS_);
    float bn1b = w_bn1_b[l] - w_bn1_m[l] * bn1s;

    union { bf16x8_t v; unsigned int u[4]; } a1[2];
#pragma unroll
    for (int half = 0; half < 2; half++) {
        const float4 f0 = *reinterpret_cast<const float4*>(w1_w + al * C_ + half * 32 + qd * 8);
        const float4 f1 = *reinterpret_cast<const float4*>(w1_w + al * C_ + half * 32 + qd * 8 + 4);
        a1[half].u[0] = bfbits(f0.x) | (bfbits(f0.y) << 16);
        a1[half].u[1] = bfbits(f0.z) | (bfbits(f0.w) << 16);
        a1[half].u[2] = bfbits(f1.x) | (bfbits(f1.y) << 16);
        a1[half].u[3] = bfbits(f1.z) | (bfbits(f1.w) << 16);
    }
    union { bf16x4_t v; unsigned int u[2]; } a2;
    {
        const float4 f = *reinterpret_cast<const float4*>(w2_w + al * 16 + qd * 4);
        a2.u[0] = bfbits(f.x) | (bfbits(f.y) << 16);
        a2.u[1] = bfbits(f.z) | (bfbits(f.w) << 16);
    }
    float zsc[4], zbi[4], tbi[4];
    {
        const float4 g2  = *reinterpret_cast<const float4*>(w_bn2_g + 4 * qd);
        const float4 bb2 = *reinterpret_cast<const float4*>(w_bn2_b + 4 * qd);
        const float4 m2  = *reinterpret_cast<const float4*>(w_bn2_m + 4 * qd);
        const float4 v2  = *reinterpret_cast<const float4*>(w_bn2_v + 4 * qd);
        const float4 ub  = *reinterpret_cast<const float4*>(w1_b + 4 * qd);
        const float4 tb  = *reinterpret_cast<const float4*>(w2_b + 4 * qd);
#pragma unroll
        for (int rr = 0; rr < 4; rr++) {
            float gg = (&g2.x)[rr], vv = (&v2.x)[rr];
            float s = gg * rsqrtf(vv + EPS_);
            zsc[rr] = s;
            zbi[rr] = ((&ub.x)[rr] - (&m2.x)[rr]) * s + (&bb2.x)[rr];
            tbi[rr] = (&tb.x)[rr];
        }
    }

    const int* nb = nbr + (size_t)bn * K_;
    int idxs[K_];
#pragma unroll
    for (int kk = 0; kk < K_; kk++) idxs[kk] = nb[kk];

    unsigned int kvw[K_];
#pragma unroll
    for (int kk = 0; kk < K_; kk++)
        kvw[kk] = kv_t[(size_t)(bB + idxs[kk]) * C_ + l];

#pragma unroll
    for (int kk = 0; kk < K_; kk++) {
        float kpr = bf_lo(kvw[kk]);
        float wv_ = fmaxf(0.f, (kpr - xq) * bn1s + bn1b);
        wlds[kk * WROW + l] = (unsigned short)bfbits(wv_);
    }
    wave_fence();

    const bf16x8_t b0 = *reinterpret_cast<const bf16x8_t*>(wlds + al * WROW + qd * 8);
    const bf16x8_t b1 = *reinterpret_cast<const bf16x8_t*>(wlds + al * WROW + 32 + qd * 8);
    f32x4_t u = {0.f, 0.f, 0.f, 0.f};
    u = __builtin_amdgcn_mfma_f32_16x16x32_bf16(a1[0].v, b0, u, 0, 0, 0);
    u = __builtin_amdgcn_mfma_f32_16x16x32_bf16(a1[1].v, b1, u, 0, 0, 0);

    union { bf16x4_t v; unsigned int u2[2]; } zb;
    {
        float z0 = fmaxf(0.f, u[0] * zsc[0] + zbi[0]);
        float z1 = fmaxf(0.f, u[1] * zsc[1] + zbi[1]);
        float z2 = fmaxf(0.f, u[2] * zsc[2] + zbi[2]);
        float z3 = fmaxf(0.f, u[3] * zsc[3] + zbi[3]);
        zb.u2[0] = bfbits(z0) | (bfbits(z1) << 16);
        zb.u2[1] = bfbits(z2) | (bfbits(z3) << 16);
    }

    f32x4_t t4 = {0.f, 0.f, 0.f, 0.f};
    t4 = __builtin_amdgcn_mfma_f32_16x16x16bf16_1k(a2.v, zb.v, t4, 0, 0, 0);

    float e[4], sden[4];
#pragma unroll
    for (int rr = 0; rr < 4; rr++) {
        e[rr] = __expf(t4[rr] + tbi[rr]);
        float s = e[rr];
        s += __shfl_xor(s, 1);
        s += __shfl_xor(s, 2);
        s += __shfl_xor(s, 4);
        s += __shfl_xor(s, 8);
        sden[rr] = s;
    }
#pragma unroll
    for (int rr = 0; rr < 4; rr++)
        sfb[al * SS + 4 * qd + rr] = e[rr] * __builtin_amdgcn_rcpf(sden[rr]);
    wave_fence();

    float acc = 0.f;
#pragma unroll
    for (int kk = 0; kk < K_; kk++)
        acc = fmaf(bf_hi(kvw[kk]), sfb[kk * SS + al], acc);
    out_t[(size_t)bn * C_ + l] = acc;
}

// ---------------------------------------------------------------------------
// Kernel C: transpose [B, N, C] -> [B, C, N], 64x64 LDS tiles.
// ---------------------------------------------------------------------------
__global__ __launch_bounds__(256) void transpose_kernel(const float* __restrict__ src,
                                                        float* __restrict__ dst)
{
    __shared__ float tile[64][65];
    int b  = blockIdx.y;
    int n0 = blockIdx.x * 64;
    int t  = threadIdx.x;

    int p  = t >> 2;
    int c0 = (t & 3) * 16;
    int n  = n0 + p;
    if (n < N_) {
        const float4* s = reinterpret_cast<const float4*>(src + ((size_t)b * N_ + n) * C_ + c0);
#pragma unroll
        for (int j = 0; j < 4; j++) {
            float4 v = s[j];
            tile[p][c0 + j * 4 + 0] = v.x;
            tile[p][c0 + j * 4 + 1] = v.y;
            tile[p][c0 + j * 4 + 2] = v.z;
            tile[p][c0 + j * 4 + 3] = v.w;
        }
    }
    __syncthreads();

    int n_off = t & 63;
    int cg    = t >> 6;
    if (n0 + n_off < N_) {
#pragma unroll
        for (int j = 0; j < 16; j++) {
            int cc = cg * 16 + j;
            dst[(size_t)b * C_ * N_ + (size_t)cc * N_ + n0 + n_off] = tile[n_off][cc];
        }
    }
}

// ---------------------------------------------------------------------------
extern "C" void kernel_launch(void* const* d_in, const int* in_sizes, int n_in,
                              void* d_out, int out_size, void* d_ws, size_t ws_size,
                              hipStream_t stream)
{
    const float* coord = (const float*)d_in[0];
    const float* q     = (const float*)d_in[1];
    const float* k     = (const float*)d_in[2];
    const int*   nbr   = (const int*)d_in[3];
    const float* wq = (const float*)d_in[4];
    const float* bq = (const float*)d_in[5];
    const float* wk = (const float*)d_in[6];
    const float* bk = (const float*)d_in[7];
    const float* wv = (const float*)d_in[8];
    const float* bv = (const float*)d_in[9];
    const float* p1_w = (const float*)d_in[10];
    const float* p1_b = (const float*)d_in[11];
    const float* p_bn_g = (const float*)d_in[12];
    const float* p_bn_b = (const float*)d_in[13];
    const float* p_bn_m = (const float*)d_in[14];
    const float* p_bn_v = (const float*)d_in[15];
    const float* p2_w = (const float*)d_in[16];
    const float* p2_b = (const float*)d_in[17];
    const float* w_bn1_g = (const float*)d_in[18];
    const float* w_bn1_b = (const float*)d_in[19];
    const float* w_bn1_m = (const float*)d_in[20];
    const float* w_bn1_v = (const float*)d_in[21];
    const float* w1_w = (const float*)d_in[22];
    const float* w1_b = (const float*)d_in[23];
    const float* w_bn2_g = (const float*)d_in[24];
    const float* w_bn2_b = (const float*)d_in[25];
    const float* w_bn2_m = (const float*)d_in[26];
    const float* w_bn2_v = (const float*)d_in[27];
    const float* w2_w = (const float*)d_in[28];
    const float* w2_b = (const float*)d_in[29];

    const size_t PTS = (size_t)B_ * N_;        // 40000
    float* ws   = (float*)d_ws;
    float* xq_t = ws;                                    // [PTS][64] f32
    unsigned int* kv_t = (unsigned int*)(ws + PTS * C_); // [PTS][64] packed bf16
    float* out_t = xq_t;  // safe alias: wave bn reads xq_t[bn] before writing out_t[bn]

    proj_kernel<<<(B_ * N_) / 16, 256, 0, stream>>>(
        q, k, coord, wq, bq, wk, bk, wv, bv,
        p1_w, p1_b, p_bn_g, p_bn_b, p_bn_m, p_bn_v, p2_w, p2_b,
        xq_t, kv_t);

    attn_kernel<<<(B_ * N_) / 4, 256, 0, stream>>>(
        nbr, xq_t, kv_t,
        w_bn1_g, w_bn1_b, w_bn1_m, w_bn1_v, w1_w, w1_b,
        w_bn2_g, w_bn2_b, w_bn2_m, w_bn2_v, w2_w, w2_b,
        out_t);

    transpose_kernel<<<dim3((N_ + 63) / 64, B_), 256, 0, stream>>>(
        out_t, (float*)d_out);
}

// Round 7
// 74.306 us; speedup vs baseline: 3.5262x; 1.0041x over previous
//
#include <hip/hip_runtime.h>
#include <math.h>

#define B_ 2
#define N_ 20000
#define C_ 64
#define K_ 16
#define CS_ 16
#define EPS_ 1e-5f

typedef float f32x4_t  __attribute__((ext_vector_type(4)));
typedef short bf16x8_t __attribute__((ext_vector_type(8)));
typedef short bf16x4_t __attribute__((ext_vector_type(4)));

// bf16 round-to-nearest-even helpers
__device__ __forceinline__ unsigned int bfbits(float f)
{
    unsigned int b = __builtin_bit_cast(unsigned int, f);
    return (b + 0x7FFFu + ((b >> 16) & 1u)) >> 16;
}
__device__ __forceinline__ float bf_lo(unsigned int w)
{
    return __builtin_bit_cast(float, w << 16);
}
__device__ __forceinline__ float bf_hi(unsigned int w)
{
    return __builtin_bit_cast(float, w & 0xFFFF0000u);
}

__device__ __forceinline__ void wave_fence()
{
    __builtin_amdgcn_wave_barrier();
}

// ---------------------------------------------------------------------------
// Kernel A: projections + positional MLP, MFMA.
// Block = 256 thr = 4 waves, 16 points. The B-fragments (input columns) are
// IDENTICAL for all 4 waves, so one cooperative pass loads each q/k element
// once (8 dwords/lane instead of 32), packs bf16-pairs into LDS planes
// (u32 stride 26 -> <=2-way consumer banks), one barrier, then per-wave MFMA
// on its 16-output-channel group.
//   xq_t[pt][c] (f32)  and  kv_t[pt][c] = bf16(xk+pos) | bf16(xv+pos)<<16
// ---------------------------------------------------------------------------
__global__ __launch_bounds__(256) void proj_kernel(
    const float* __restrict__ q, const float* __restrict__ kin,
    const float* __restrict__ coord,
    const float* __restrict__ wq, const float* __restrict__ bq,
    const float* __restrict__ wk, const float* __restrict__ bk,
    const float* __restrict__ wv, const float* __restrict__ bv,
    const float* __restrict__ p1_w, const float* __restrict__ p1_b,
    const float* __restrict__ p_bn_g, const float* __restrict__ p_bn_b,
    const float* __restrict__ p_bn_m, const float* __restrict__ p_bn_v,
    const float* __restrict__ p2_w, const float* __restrict__ p2_b,
    float* __restrict__ xq_t, unsigned int* __restrict__ kv_t)
{
    constexpr int PS = 26;                    // LDS u32 stride per ci-pair row
    __shared__ unsigned int qp[32 * PS];      // packed (q[2cp], q[2cp+1]) bf16
    __shared__ unsigned int kp[32 * PS];

    const int t   = threadIdx.x;
    const int og  = __builtin_amdgcn_readfirstlane(t >> 6);  // wave's channel group
    const int l   = t & 63;
    const int col = l & 15;          // point within 16-pt tile (B col / C col)
    const int qd  = l >> 4;          // k-chunk / C row-quad
    const int pt0 = blockIdx.x * 16; // 2500 blocks; 20000%16==0, no straddle
    const int pt  = pt0 + col;
    const int b   = pt0 / N_;
    const int n   = pt - b * N_;
    const size_t cb = (size_t)b * C_ * N_ + n;

    // ---- cooperative B-tile load: wave og covers ci-pairs og*8 .. og*8+7 ----
#pragma unroll
    for (int r = 0; r < 2; r++) {
        int cp = (og << 3) + (qd << 1) + r;   // ci-pair index
        int ci = cp * 2;
        float q0 = q[cb + (size_t)ci * N_];
        float q1 = q[cb + (size_t)(ci + 1) * N_];
        float k0 = kin[cb + (size_t)ci * N_];
        float k1 = kin[cb + (size_t)(ci + 1) * N_];
        qp[cp * PS + col] = bfbits(q0) | (bfbits(q1) << 16);
        kp[cp * PS + col] = bfbits(k0) | (bfbits(k1) << 16);
    }

    // ---- A-fragments (weight rows, row = og*16+col) ----
    union bf8u { bf16x8_t v; unsigned int u[4]; };
    const int arow = og * 16 + col;
    bf8u awq[2], awk[2], awv[2];
#pragma unroll
    for (int half = 0; half < 2; half++) {
        const float4 fq0 = *reinterpret_cast<const float4*>(wq + (size_t)arow * C_ + half * 32 + qd * 8);
        const float4 fq1 = *reinterpret_cast<const float4*>(wq + (size_t)arow * C_ + half * 32 + qd * 8 + 4);
        const float4 fk0 = *reinterpret_cast<const float4*>(wk + (size_t)arow * C_ + half * 32 + qd * 8);
        const float4 fk1 = *reinterpret_cast<const float4*>(wk + (size_t)arow * C_ + half * 32 + qd * 8 + 4);
        const float4 fv0 = *reinterpret_cast<const float4*>(wv + (size_t)arow * C_ + half * 32 + qd * 8);
        const float4 fv1 = *reinterpret_cast<const float4*>(wv + (size_t)arow * C_ + half * 32 + qd * 8 + 4);
        awq[half].u[0] = bfbits(fq0.x) | (bfbits(fq0.y) << 16);
        awq[half].u[1] = bfbits(fq0.z) | (bfbits(fq0.w) << 16);
        awq[half].u[2] = bfbits(fq1.x) | (bfbits(fq1.y) << 16);
        awq[half].u[3] = bfbits(fq1.z) | (bfbits(fq1.w) << 16);
        awk[half].u[0] = bfbits(fk0.x) | (bfbits(fk0.y) << 16);
        awk[half].u[1] = bfbits(fk0.z) | (bfbits(fk0.w) << 16);
        awk[half].u[2] = bfbits(fk1.x) | (bfbits(fk1.y) << 16);
        awk[half].u[3] = bfbits(fk1.z) | (bfbits(fk1.w) << 16);
        awv[half].u[0] = bfbits(fv0.x) | (bfbits(fv0.y) << 16);
        awv[half].u[1] = bfbits(fv0.z) | (bfbits(fv0.w) << 16);
        awv[half].u[2] = bfbits(fv1.x) | (bfbits(fv1.y) << 16);
        awv[half].u[3] = bfbits(fv1.z) | (bfbits(fv1.w) << 16);
    }

    __syncthreads();

    // ---- B-fragments from LDS ----
    bf8u bq_[2], bk_[2];
#pragma unroll
    for (int half = 0; half < 2; half++) {
#pragma unroll
        for (int i2 = 0; i2 < 4; i2++) {
            int cp = half * 16 + qd * 4 + i2;
            bq_[half].u[i2] = qp[cp * PS + col];
            bk_[half].u[i2] = kp[cp * PS + col];
        }
    }

    // ---- MFMAs ----
    f32x4_t uq = {0.f, 0.f, 0.f, 0.f};
    f32x4_t uv = {0.f, 0.f, 0.f, 0.f};
    f32x4_t uk = {0.f, 0.f, 0.f, 0.f};
    uq = __builtin_amdgcn_mfma_f32_16x16x32_bf16(awq[0].v, bq_[0].v, uq, 0, 0, 0);
    uq = __builtin_amdgcn_mfma_f32_16x16x32_bf16(awq[1].v, bq_[1].v, uq, 0, 0, 0);
    uv = __builtin_amdgcn_mfma_f32_16x16x32_bf16(awv[0].v, bq_[0].v, uv, 0, 0, 0);
    uv = __builtin_amdgcn_mfma_f32_16x16x32_bf16(awv[1].v, bq_[1].v, uv, 0, 0, 0);
    uk = __builtin_amdgcn_mfma_f32_16x16x32_bf16(awk[0].v, bk_[0].v, uk, 0, 0, 0);
    uk = __builtin_amdgcn_mfma_f32_16x16x32_bf16(awk[1].v, bk_[1].v, uk, 0, 0, 0);

    // ---- positional MLP for the lane's point, channels ch0..ch0+3 ----
    float pbs[3], pbb[3];
#pragma unroll
    for (int j = 0; j < 3; j++) {
        float s = p_bn_g[j] * rsqrtf(p_bn_v[j] + EPS_);
        pbs[j] = s;
        pbb[j] = (p1_b[j] - p_bn_m[j]) * s + p_bn_b[j];
    }
    float cx = coord[pt * 3 + 0], cy = coord[pt * 3 + 1], cz = coord[pt * 3 + 2];
    float h0 = fmaxf(0.f, (p1_w[0]*cx + p1_w[1]*cy + p1_w[2]*cz) * pbs[0] + pbb[0]);
    float h1 = fmaxf(0.f, (p1_w[3]*cx + p1_w[4]*cy + p1_w[5]*cz) * pbs[1] + pbb[1]);
    float h2 = fmaxf(0.f, (p1_w[6]*cx + p1_w[7]*cy + p1_w[8]*cz) * pbs[2] + pbb[2]);

    const int ch0 = og * 16 + qd * 4;
    float pos[4];
#pragma unroll
    for (int rr = 0; rr < 4; rr++) {
        int ch = ch0 + rr;
        pos[rr] = fmaf(p2_w[ch*3+0], h0, fmaf(p2_w[ch*3+1], h1,
                  fmaf(p2_w[ch*3+2], h2, p2_b[ch])));
    }

    // ---- epilogue: biases + stores ----
    const float4 bqv = *reinterpret_cast<const float4*>(bq + ch0);
    const float4 bkv = *reinterpret_cast<const float4*>(bk + ch0);
    const float4 bvv = *reinterpret_cast<const float4*>(bv + ch0);

    float4 xqo;
    xqo.x = uq[0] + bqv.x; xqo.y = uq[1] + bqv.y;
    xqo.z = uq[2] + bqv.z; xqo.w = uq[3] + bqv.w;
    *reinterpret_cast<float4*>(xq_t + (size_t)pt * C_ + ch0) = xqo;

    uint4 kvo;
#pragma unroll
    for (int rr = 0; rr < 4; rr++) {
        float kk = uk[rr] + (&bkv.x)[rr] + pos[rr];
        float vv = uv[rr] + (&bvv.x)[rr] + pos[rr];
        (&kvo.x)[rr] = bfbits(kk) | (bfbits(vv) << 16);
    }
    *reinterpret_cast<uint4*>(kv_t + (size_t)pt * C_ + ch0) = kvo;
}

// ---------------------------------------------------------------------------
// Kernel B: attention via MFMA + fused transposed output.
// Block = 1024 thr = 16 waves = 16 consecutive points; wave-private LDS for
// the per-point pipeline (no barriers), then ONE __syncthreads and a
// coalesced [B,C,N] write from a 64x16 LDS out-tile (64B rows).
// LDS: 16*2304 (w tiles) + 16*1088 (softmax) + 4352 (out) = 58624B
//   -> exactly 2 blocks/CU = 32 waves/CU. launch_bounds(1024,8) caps VGPR 64.
// ---------------------------------------------------------------------------
__global__ __launch_bounds__(1024, 8) void attn_kernel(
    const int* __restrict__ nbr,
    const float* __restrict__ xq_t, const unsigned int* __restrict__ kv_t,
    const float* __restrict__ w_bn1_g, const float* __restrict__ w_bn1_b,
    const float* __restrict__ w_bn1_m, const float* __restrict__ w_bn1_v,
    const float* __restrict__ w1_w, const float* __restrict__ w1_b,
    const float* __restrict__ w_bn2_g, const float* __restrict__ w_bn2_b,
    const float* __restrict__ w_bn2_m, const float* __restrict__ w_bn2_v,
    const float* __restrict__ w2_w, const float* __restrict__ w2_b,
    float* __restrict__ out)
{
    constexpr int WROW = 72;              // bf16 elems per w-tile row (144B)
    constexpr int WN   = K_ * WROW;       // 1152 ushort per point
    constexpr int SS   = 17;
    constexpr int SN   = K_ * SS;         // 272 f32 per point
    __shared__ unsigned short wlds_all[16 * WN];   // 36864B
    __shared__ float          sfb_all[16 * SN];    // 17408B
    __shared__ float          otile[64 * 17];      // 4352B

    const int w  = __builtin_amdgcn_readfirstlane(threadIdx.x >> 6);  // point in tile
    const int l  = threadIdx.x & 63;
    const int al = l & 15;
    const int qd = l >> 4;

    const int pt0 = blockIdx.x * 16;      // 2500 blocks; no batch straddle
    const int b   = pt0 / N_;
    const int bB  = b * N_;
    const int bn  = pt0 + w;

    unsigned short* wlds = wlds_all + w * WN;
    float*          sfb  = sfb_all + w * SN;

    float xq   = xq_t[(size_t)bn * C_ + l];
    float bn1s = w_bn1_g[l] * rsqrtf(w_bn1_v[l] + EPS_);
    float bn1b = w_bn1_b[l] - w_bn1_m[l] * bn1s;

    union { bf16x8_t v; unsigned int u[4]; } a1[2];
#pragma unroll
    for (int half = 0; half < 2; half++) {
        const float4 f0 = *reinterpret_cast<const float4*>(w1_w + al * C_ + half * 32 + qd * 8);
        const float4 f1 = *reinterpret_cast<const float4*>(w1_w + al * C_ + half * 32 + qd * 8 + 4);
        a1[half].u[0] = bfbits(f0.x) | (bfbits(f0.y) << 16);
        a1[half].u[1] = bfbits(f0.z) | (bfbits(f0.w) << 16);
        a1[half].u[2] = bfbits(f1.x) | (bfbits(f1.y) << 16);
        a1[half].u[3] = bfbits(f1.z) | (bfbits(f1.w) << 16);
    }
    union { bf16x4_t v; unsigned int u[2]; } a2;
    {
        const float4 f = *reinterpret_cast<const float4*>(w2_w + al * 16 + qd * 4);
        a2.u[0] = bfbits(f.x) | (bfbits(f.y) << 16);
        a2.u[1] = bfbits(f.z) | (bfbits(f.w) << 16);
    }
    float zsc[4], zbi[4], tbi[4];
    {
        const float4 g2  = *reinterpret_cast<const float4*>(w_bn2_g + 4 * qd);
        const float4 bb2 = *reinterpret_cast<const float4*>(w_bn2_b + 4 * qd);
        const float4 m2  = *reinterpret_cast<const float4*>(w_bn2_m + 4 * qd);
        const float4 v2  = *reinterpret_cast<const float4*>(w_bn2_v + 4 * qd);
        const float4 ub  = *reinterpret_cast<const float4*>(w1_b + 4 * qd);
        const float4 tb  = *reinterpret_cast<const float4*>(w2_b + 4 * qd);
#pragma unroll
        for (int rr = 0; rr < 4; rr++) {
            float gg = (&g2.x)[rr], vv = (&v2.x)[rr];
            float s = gg * rsqrtf(vv + EPS_);
            zsc[rr] = s;
            zbi[rr] = ((&ub.x)[rr] - (&m2.x)[rr]) * s + (&bb2.x)[rr];
            tbi[rr] = (&tb.x)[rr];
        }
    }

    // ---- phase 1: gather packed bf16 rows ----
    const int* nb = nbr + (size_t)bn * K_;
    int idxs[K_];
#pragma unroll
    for (int kk = 0; kk < K_; kk++) idxs[kk] = nb[kk];     // uniform -> s_load

    unsigned int kvw[K_];
#pragma unroll
    for (int kk = 0; kk < K_; kk++)
        kvw[kk] = kv_t[(size_t)(bB + idxs[kk]) * C_ + l];  // coalesced 256B rows

#pragma unroll
    for (int kk = 0; kk < K_; kk++) {
        float kpr = bf_lo(kvw[kk]);                        // xk + pos
        float wv_ = fmaxf(0.f, (kpr - xq) * bn1s + bn1b);
        wlds[kk * WROW + l] = (unsigned short)bfbits(wv_);
    }
    wave_fence();

    // ---- phase 2a: u = w1 @ w^T ----
    const bf16x8_t b0 = *reinterpret_cast<const bf16x8_t*>(wlds + al * WROW + qd * 8);
    const bf16x8_t b1 = *reinterpret_cast<const bf16x8_t*>(wlds + al * WROW + 32 + qd * 8);
    f32x4_t u = {0.f, 0.f, 0.f, 0.f};
    u = __builtin_amdgcn_mfma_f32_16x16x32_bf16(a1[0].v, b0, u, 0, 0, 0);
    u = __builtin_amdgcn_mfma_f32_16x16x32_bf16(a1[1].v, b1, u, 0, 0, 0);

    union { bf16x4_t v; unsigned int u2[2]; } zb;
    {
        float z0 = fmaxf(0.f, u[0] * zsc[0] + zbi[0]);
        float z1 = fmaxf(0.f, u[1] * zsc[1] + zbi[1]);
        float z2 = fmaxf(0.f, u[2] * zsc[2] + zbi[2]);
        float z3 = fmaxf(0.f, u[3] * zsc[3] + zbi[3]);
        zb.u2[0] = bfbits(z0) | (bfbits(z1) << 16);
        zb.u2[1] = bfbits(z2) | (bfbits(z3) << 16);
    }

    // ---- phase 2b: t = w2 @ z ----
    f32x4_t t4 = {0.f, 0.f, 0.f, 0.f};
    t4 = __builtin_amdgcn_mfma_f32_16x16x16bf16_1k(a2.v, zb.v, t4, 0, 0, 0);

    // ---- softmax over neighbors per row g = 4*qd+rr ----
    float e[4], sden[4];
#pragma unroll
    for (int rr = 0; rr < 4; rr++) {
        e[rr] = __expf(t4[rr] + tbi[rr]);
        float s = e[rr];
        s += __shfl_xor(s, 1);
        s += __shfl_xor(s, 2);
        s += __shfl_xor(s, 4);
        s += __shfl_xor(s, 8);
        sden[rr] = s;
    }
#pragma unroll
    for (int rr = 0; rr < 4; rr++)
        sfb[al * SS + 4 * qd + rr] = e[rr] * __builtin_amdgcn_rcpf(sden[rr]);
    wave_fence();

    // ---- phase 3: out[c] = sum_k v[k] * soft[c&15][k] -> LDS out tile ----
    float acc = 0.f;
#pragma unroll
    for (int kk = 0; kk < K_; kk++)
        acc = fmaf(bf_hi(kvw[kk]), sfb[kk * SS + al], acc);
    otile[l * 17 + w] = acc;

    __syncthreads();

    // ---- coalesced [B,C,N] write: thread t -> (c = t>>4, n = n0 + (t&15)) ----
    {
        int c  = threadIdx.x >> 4;
        int nn = threadIdx.x & 15;
        out[(size_t)b * C_ * N_ + (size_t)c * N_ + (pt0 - bB) + nn] = otile[c * 17 + nn];
    }
}

// ---------------------------------------------------------------------------
extern "C" void kernel_launch(void* const* d_in, const int* in_sizes, int n_in,
                              void* d_out, int out_size, void* d_ws, size_t ws_size,
                              hipStream_t stream)
{
    const float* coord = (const float*)d_in[0];
    const float* q     = (const float*)d_in[1];
    const float* k     = (const float*)d_in[2];
    const int*   nbr   = (const int*)d_in[3];
    const float* wq = (const float*)d_in[4];
    const float* bq = (const float*)d_in[5];
    const float* wk = (const float*)d_in[6];
    const float* bk = (const float*)d_in[7];
    const float* wv = (const float*)d_in[8];
    const float* bv = (const float*)d_in[9];
    const float* p1_w = (const float*)d_in[10];
    const float* p1_b = (const float*)d_in[11];
    const float* p_bn_g = (const float*)d_in[12];
    const float* p_bn_b = (const float*)d_in[13];
    const float* p_bn_m = (const float*)d_in[14];
    const float* p_bn_v = (const float*)d_in[15];
    const float* p2_w = (const float*)d_in[16];
    const float* p2_b = (const float*)d_in[17];
    const float* w_bn1_g = (const float*)d_in[18];
    const float* w_bn1_b = (const float*)d_in[19];
    const float* w_bn1_m = (const float*)d_in[20];
    const float* w_bn1_v = (const float*)d_in[21];
    const float* w1_w = (const float*)d_in[22];
    const float* w1_b = (const float*)d_in[23];
    const float* w_bn2_g = (const float*)d_in[24];
    const float* w_bn2_b = (const float*)d_in[25];
    const float* w_bn2_m = (const float*)d_in[26];
    const float* w_bn2_v = (const float*)d_in[27];
    const float* w2_w = (const float*)d_in[28];
    const float* w2_b = (const float*)d_in[29];

    const size_t PTS = (size_t)B_ * N_;        // 40000
    float* ws   = (float*)d_ws;
    float* xq_t = ws;                                    // [PTS][64] f32
    unsigned int* kv_t = (unsigned int*)(ws + PTS * C_); // [PTS][64] packed bf16

    proj_kernel<<<(B_ * N_) / 16, 256, 0, stream>>>(
        q, k, coord, wq, bq, wk, bk, wv, bv,
        p1_w, p1_b, p_bn_g, p_bn_b, p_bn_m, p_bn_v, p2_w, p2_b,
        xq_t, kv_t);

    attn_kernel<<<(B_ * N_) / 16, 1024, 0, stream>>>(
        nbr, xq_t, kv_t,
        w_bn1_g, w_bn1_b, w_bn1_m, w_bn1_v, w1_w, w1_b,
        w_bn2_g, w_bn2_b, w_bn2_m, w_bn2_v, w2_w, w2_b,
        (float*)d_out);
}

// Round 8
// 49.387 us; speedup vs baseline: 5.3053x; 1.5046x over previous
//
#include <hip/hip_runtime.h>
#include <math.h>

#define B_ 2
#define N_ 20000
#define C_ 64
#define K_ 16
#define CS_ 16
#define EPS_ 1e-5f

typedef float f32x4_t  __attribute__((ext_vector_type(4)));
typedef short bf16x8_t __attribute__((ext_vector_type(8)));
typedef short bf16x4_t __attribute__((ext_vector_type(4)));

// bf16 round-to-nearest-even helpers
__device__ __forceinline__ unsigned int bfbits(float f)
{
    unsigned int b = __builtin_bit_cast(unsigned int, f);
    return (b + 0x7FFFu + ((b >> 16) & 1u)) >> 16;
}
__device__ __forceinline__ float bf_lo(unsigned int w)
{
    return __builtin_bit_cast(float, w << 16);
}
__device__ __forceinline__ float bf_hi(unsigned int w)
{
    return __builtin_bit_cast(float, w & 0xFFFF0000u);
}
__device__ __forceinline__ void wave_fence()
{
    __builtin_amdgcn_wave_barrier();
}
__device__ __forceinline__ unsigned int pk2(const float* p)
{
    return bfbits(p[0]) | (bfbits(p[1]) << 16);
}

// ---------------------------------------------------------------------------
// Kernel 0: one-block setup. Precomputes bf16 A-fragment tables (wq/wk/wv for
// proj; w1/w2 for attn) and folded bn2 constants, so the 50000 worker waves
// load fragments as dwordx4 instead of re-packing them (~150 VALU each).
//   wtab[m*512 + og*128 + half*64 + l]  (uint4)   m in {q,k,v}
//   a1tab[half*64 + l] (uint4),  a2tab[l] (uint2)
//   cz[0..15]=zsc, cz[16..31]=zbi, cz[32..47]=tbi
// ---------------------------------------------------------------------------
__global__ __launch_bounds__(256) void setup_kernel(
    const float* __restrict__ wq, const float* __restrict__ wk,
    const float* __restrict__ wv,
    const float* __restrict__ w1_w, const float* __restrict__ w1_b,
    const float* __restrict__ w2_w, const float* __restrict__ w2_b,
    const float* __restrict__ w_bn2_g, const float* __restrict__ w_bn2_b,
    const float* __restrict__ w_bn2_m, const float* __restrict__ w_bn2_v,
    uint4* __restrict__ wtab, uint4* __restrict__ a1tab,
    uint2* __restrict__ a2tab, float* __restrict__ cz)
{
    const int t = threadIdx.x;
    for (int e = t; e < 1536; e += 256) {
        int m = e >> 9, rem = e & 511;
        int og = rem >> 7, half = (rem >> 6) & 1, l = rem & 63;
        const float* W = (m == 0) ? wq : ((m == 1) ? wk : wv);
        const float* base = W + (size_t)(og * 16 + (l & 15)) * C_ + half * 32 + (l >> 4) * 8;
        uint4 o;
        o.x = pk2(base + 0); o.y = pk2(base + 2);
        o.z = pk2(base + 4); o.w = pk2(base + 6);
        wtab[e] = o;
    }
    if (t < 128) {
        int half = t >> 6, l = t & 63;
        const float* base = w1_w + (size_t)(l & 15) * C_ + half * 32 + (l >> 4) * 8;
        uint4 o;
        o.x = pk2(base + 0); o.y = pk2(base + 2);
        o.z = pk2(base + 4); o.w = pk2(base + 6);
        a1tab[t] = o;
    }
    if (t < 64) {
        const float* base = w2_w + (t & 15) * 16 + (t >> 4) * 4;
        uint2 o;
        o.x = pk2(base + 0); o.y = pk2(base + 2);
        a2tab[t] = o;
    }
    if (t < 16) {
        float s = w_bn2_g[t] * rsqrtf(w_bn2_v[t] + EPS_);
        cz[t]      = s;
        cz[16 + t] = (w1_b[t] - w_bn2_m[t]) * s + w_bn2_b[t];
        cz[32 + t] = w2_b[t];
    }
}

// ---------------------------------------------------------------------------
// Kernel A: projections + positional MLP + bn1 fold, MFMA.
// Block = 256 thr = 4 waves, 16 points; cooperative bf16 input tile in LDS;
// A-frags from wtab (dwordx4 loads). Outputs:
//   xq2[pt][c]  = bn1s*xq - bn1bf          (f32; w = relu(kvlo - xq2))
//   kv_t[pt][c] = bf16(bn1s*(xk+pos)) | bf16(xv+pos)<<16
// ---------------------------------------------------------------------------
__global__ __launch_bounds__(256) void proj_kernel(
    const float* __restrict__ q, const float* __restrict__ kin,
    const float* __restrict__ coord,
    const float* __restrict__ bq, const float* __restrict__ bk,
    const float* __restrict__ bv,
    const float* __restrict__ p1_w, const float* __restrict__ p1_b,
    const float* __restrict__ p_bn_g, const float* __restrict__ p_bn_b,
    const float* __restrict__ p_bn_m, const float* __restrict__ p_bn_v,
    const float* __restrict__ p2_w, const float* __restrict__ p2_b,
    const float* __restrict__ w_bn1_g, const float* __restrict__ w_bn1_b,
    const float* __restrict__ w_bn1_m, const float* __restrict__ w_bn1_v,
    const uint4* __restrict__ wtab,
    float* __restrict__ xq2, unsigned int* __restrict__ kv_t)
{
    constexpr int PS = 26;
    __shared__ unsigned int qp[32 * PS];
    __shared__ unsigned int kp[32 * PS];

    const int t   = threadIdx.x;
    const int og  = __builtin_amdgcn_readfirstlane(t >> 6);
    const int l   = t & 63;
    const int col = l & 15;
    const int qd  = l >> 4;
    const int pt0 = blockIdx.x * 16;
    const int pt  = pt0 + col;
    const int b   = pt0 / N_;
    const int n   = pt - b * N_;
    const size_t cb = (size_t)b * C_ * N_ + n;

    // cooperative input tile (each element loaded once per block)
#pragma unroll
    for (int r = 0; r < 2; r++) {
        int cp = (og << 3) + (qd << 1) + r;
        int ci = cp * 2;
        float q0 = q[cb + (size_t)ci * N_];
        float q1 = q[cb + (size_t)(ci + 1) * N_];
        float k0 = kin[cb + (size_t)ci * N_];
        float k1 = kin[cb + (size_t)(ci + 1) * N_];
        qp[cp * PS + col] = bfbits(q0) | (bfbits(q1) << 16);
        kp[cp * PS + col] = bfbits(k0) | (bfbits(k1) << 16);
    }

    // A-fragments from table
    union bf8u { bf16x8_t v; uint4 u4; };
    bf8u awq[2], awk[2], awv[2];
#pragma unroll
    for (int half = 0; half < 2; half++) {
        awq[half].u4 = wtab[0 * 512 + og * 128 + half * 64 + l];
        awk[half].u4 = wtab[1 * 512 + og * 128 + half * 64 + l];
        awv[half].u4 = wtab[2 * 512 + og * 128 + half * 64 + l];
    }

    __syncthreads();

    union bf8b { bf16x8_t v; unsigned int u[4]; };
    bf8b bq_[2], bk_[2];
#pragma unroll
    for (int half = 0; half < 2; half++) {
#pragma unroll
        for (int i2 = 0; i2 < 4; i2++) {
            int cp = half * 16 + qd * 4 + i2;
            bq_[half].u[i2] = qp[cp * PS + col];
            bk_[half].u[i2] = kp[cp * PS + col];
        }
    }

    f32x4_t uq = {0.f, 0.f, 0.f, 0.f};
    f32x4_t uv = {0.f, 0.f, 0.f, 0.f};
    f32x4_t uk = {0.f, 0.f, 0.f, 0.f};
    uq = __builtin_amdgcn_mfma_f32_16x16x32_bf16(awq[0].v, bq_[0].v, uq, 0, 0, 0);
    uq = __builtin_amdgcn_mfma_f32_16x16x32_bf16(awq[1].v, bq_[1].v, uq, 0, 0, 0);
    uv = __builtin_amdgcn_mfma_f32_16x16x32_bf16(awv[0].v, bq_[0].v, uv, 0, 0, 0);
    uv = __builtin_amdgcn_mfma_f32_16x16x32_bf16(awv[1].v, bq_[1].v, uv, 0, 0, 0);
    uk = __builtin_amdgcn_mfma_f32_16x16x32_bf16(awk[0].v, bk_[0].v, uk, 0, 0, 0);
    uk = __builtin_amdgcn_mfma_f32_16x16x32_bf16(awk[1].v, bk_[1].v, uk, 0, 0, 0);

    // positional MLP for this point's 4 channels
    float pbs[3], pbb[3];
#pragma unroll
    for (int j = 0; j < 3; j++) {
        float s = p_bn_g[j] * rsqrtf(p_bn_v[j] + EPS_);
        pbs[j] = s;
        pbb[j] = (p1_b[j] - p_bn_m[j]) * s + p_bn_b[j];
    }
    float cx = coord[pt * 3 + 0], cy = coord[pt * 3 + 1], cz = coord[pt * 3 + 2];
    float h0 = fmaxf(0.f, (p1_w[0]*cx + p1_w[1]*cy + p1_w[2]*cz) * pbs[0] + pbb[0]);
    float h1 = fmaxf(0.f, (p1_w[3]*cx + p1_w[4]*cy + p1_w[5]*cz) * pbs[1] + pbb[1]);
    float h2 = fmaxf(0.f, (p1_w[6]*cx + p1_w[7]*cy + p1_w[8]*cz) * pbs[2] + pbb[2]);

    const int ch0 = og * 16 + qd * 4;
    float pos[4];
#pragma unroll
    for (int rr = 0; rr < 4; rr++) {
        int ch = ch0 + rr;
        pos[rr] = fmaf(p2_w[ch*3+0], h0, fmaf(p2_w[ch*3+1], h1,
                  fmaf(p2_w[ch*3+2], h2, p2_b[ch])));
    }

    // epilogue: biases + bn1 fold + stores
    const float4 bqv = *reinterpret_cast<const float4*>(bq + ch0);
    const float4 bkv = *reinterpret_cast<const float4*>(bk + ch0);
    const float4 bvv = *reinterpret_cast<const float4*>(bv + ch0);
    const float4 g1  = *reinterpret_cast<const float4*>(w_bn1_g + ch0);
    const float4 b1  = *reinterpret_cast<const float4*>(w_bn1_b + ch0);
    const float4 m1  = *reinterpret_cast<const float4*>(w_bn1_m + ch0);
    const float4 v1  = *reinterpret_cast<const float4*>(w_bn1_v + ch0);

    float4 xqo;
    uint4 kvo;
#pragma unroll
    for (int rr = 0; rr < 4; rr++) {
        float s   = (&g1.x)[rr] * rsqrtf((&v1.x)[rr] + EPS_);
        float b1f = (&b1.x)[rr] - (&m1.x)[rr] * s;
        float xqv = uq[rr] + (&bqv.x)[rr];
        (&xqo.x)[rr] = s * xqv - b1f;                       // xq2
        float kk = s * (uk[rr] + (&bkv.x)[rr] + pos[rr]);   // pre-scaled k
        float vv = uv[rr] + (&bvv.x)[rr] + pos[rr];
        (&kvo.x)[rr] = bfbits(kk) | (bfbits(vv) << 16);
    }
    *reinterpret_cast<float4*>(xq2 + (size_t)pt * C_ + ch0) = xqo;
    *reinterpret_cast<uint4*>(kv_t + (size_t)pt * C_ + ch0) = kvo;
}

// ---------------------------------------------------------------------------
// Kernel B: attention via MFMA, fused transposed output.
// Block = 1024 thr = 16 waves = 16 consecutive points.
// Phase1/3 lane roles: cpair = l&31 (2 channels c0=2*cpair), kh = l>>5
//   (8 neighbors k = kh*8+j): 8x dwordx2 gathers, w = relu(lo - xq2),
//   packed pair -> 8x ds_write_b32 into the [k][c] bf16 w-tile.
// Phase2 roles (al = l&15, qd = l>>4): 2x mfma 16x16x32 (w1@w^T),
//   bn2/relu in regs, 1x mfma 16x16x16 (w2@z), softmax over k via DPP
//   shuffles; weights staged [k][g] with ds_write_b128.
// Phase3: per-lane 8-k partial sums for 2 channels, shfl_xor(32) combine,
//   LDS out-tile, one __syncthreads, coalesced [B,C,N] store.
// LDS 61696B -> 2 blocks/CU = 32 waves/CU.
// ---------------------------------------------------------------------------
#define WROW 72          // ushorts per w-tile row (144B)
#define WPN  (K_ * WROW) // 1152 per point
#define SS4  20          // sfb row stride (f32)
#define SPN  (K_ * SS4)  // 320 per point

__global__ __launch_bounds__(1024, 8) void attn_kernel(
    const int* __restrict__ nbr,
    const float* __restrict__ xq2, const unsigned int* __restrict__ kv_t,
    const uint4* __restrict__ a1tab, const uint2* __restrict__ a2tab,
    const float* __restrict__ cz,
    float* __restrict__ out)
{
    __shared__ unsigned short wlds_all[16 * WPN];   // 36864B
    __shared__ float          sfb_all[16 * SPN];    // 20480B
    __shared__ float          otile[64 * 17];       //  4352B

    const int w  = __builtin_amdgcn_readfirstlane(threadIdx.x >> 6);
    const int l  = threadIdx.x & 63;
    const int al = l & 15;
    const int qd = l >> 4;
    const int cpair = l & 31;
    const int kh    = l >> 5;
    const int c0    = cpair * 2;

    const int pt0 = blockIdx.x * 16;
    const int b   = pt0 / N_;
    const int bB  = b * N_;
    const int bn  = pt0 + w;

    unsigned short* wlds = wlds_all + w * WPN;
    float*          sfb  = sfb_all + w * SPN;

    // constants from tables (no per-wave packing)
    union bf8u { bf16x8_t v; uint4 u4; };
    union bf4u { bf16x4_t v; uint2 u2; };
    bf8u a1q0, a1q1; bf4u a2q;
    a1q0.u4 = a1tab[l];
    a1q1.u4 = a1tab[64 + l];
    a2q.u2  = a2tab[l];
    const float4 zsc4 = *reinterpret_cast<const float4*>(cz + qd * 4);
    const float4 zbi4 = *reinterpret_cast<const float4*>(cz + 16 + qd * 4);
    const float4 tbi4 = *reinterpret_cast<const float4*>(cz + 32 + qd * 4);
    const float2 xqp  = *reinterpret_cast<const float2*>(xq2 + (size_t)bn * C_ + c0);

    // ---- phase 1: gather 8 neighbor rows x 2 channels ----
    const int* nb = nbr + (size_t)bn * K_;
    uint2 kvw[8];
#pragma unroll
    for (int j = 0; j < 8; j++) {
        int ia = nb[j];            // wave-uniform -> s_load
        int ib = nb[8 + j];
        int idx = (kh != 0) ? ib : ia;
        kvw[j] = *reinterpret_cast<const uint2*>(kv_t + ((size_t)(bB + idx) * C_ + c0));
    }
#pragma unroll
    for (int j = 0; j < 8; j++) {
        float w0 = fmaxf(0.f, bf_lo(kvw[j].x) - xqp.x);
        float w1 = fmaxf(0.f, bf_lo(kvw[j].y) - xqp.y);
        unsigned int pkw = bfbits(w0) | (bfbits(w1) << 16);
        *reinterpret_cast<unsigned int*>(wlds + (kh * 8 + j) * WROW + c0) = pkw;
    }
    wave_fence();

    // ---- phase 2a: u = w1 @ w^T ----
    const bf16x8_t b0 = *reinterpret_cast<const bf16x8_t*>(wlds + al * WROW + qd * 8);
    const bf16x8_t b1 = *reinterpret_cast<const bf16x8_t*>(wlds + al * WROW + 32 + qd * 8);
    f32x4_t u = {0.f, 0.f, 0.f, 0.f};
    u = __builtin_amdgcn_mfma_f32_16x16x32_bf16(a1q0.v, b0, u, 0, 0, 0);
    u = __builtin_amdgcn_mfma_f32_16x16x32_bf16(a1q1.v, b1, u, 0, 0, 0);

    union { bf16x4_t v; unsigned int u2[2]; } zb;
    {
        float z0 = fmaxf(0.f, u[0] * zsc4.x + zbi4.x);
        float z1 = fmaxf(0.f, u[1] * zsc4.y + zbi4.y);
        float z2 = fmaxf(0.f, u[2] * zsc4.z + zbi4.z);
        float z3 = fmaxf(0.f, u[3] * zsc4.w + zbi4.w);
        zb.u2[0] = bfbits(z0) | (bfbits(z1) << 16);
        zb.u2[1] = bfbits(z2) | (bfbits(z3) << 16);
    }

    // ---- phase 2b: t = w2 @ z ----
    f32x4_t t4 = {0.f, 0.f, 0.f, 0.f};
    t4 = __builtin_amdgcn_mfma_f32_16x16x16bf16_1k(a2q.v, zb.v, t4, 0, 0, 0);

    // ---- softmax over neighbors, rows g = 4qd+rr, col k = al ----
    float4 sv;
#pragma unroll
    for (int rr = 0; rr < 4; rr++) {
        float e = __expf(t4[rr] + (&tbi4.x)[rr]);   // |t| << 80, no max-sub
        float s = e;
        s += __shfl_xor(s, 1);
        s += __shfl_xor(s, 2);
        s += __shfl_xor(s, 4);
        s += __shfl_xor(s, 8);
        (&sv.x)[rr] = e * __builtin_amdgcn_rcpf(s);
    }
    *reinterpret_cast<float4*>(sfb + al * SS4 + qd * 4) = sv;  // [k][g] row al
    wave_fence();

    // ---- phase 3: out[c] = sum_k v[k][c] * soft[k][c&15] ----
    const int g0 = c0 & 15;
    float acc0 = 0.f, acc1 = 0.f;
#pragma unroll
    for (int j = 0; j < 8; j++) {
        float2 sp = *reinterpret_cast<const float2*>(sfb + (kh * 8 + j) * SS4 + g0);
        acc0 = fmaf(bf_hi(kvw[j].x), sp.x, acc0);
        acc1 = fmaf(bf_hi(kvw[j].y), sp.y, acc1);
    }
    acc0 += __shfl_xor(acc0, 32);
    acc1 += __shfl_xor(acc1, 32);
    if (kh == 0) {
        otile[c0 * 17 + w]       = acc0;
        otile[(c0 + 1) * 17 + w] = acc1;
    }
    __syncthreads();

    // coalesced [B,C,N] write: thread t -> (c = t>>4, n = pt0%N + (t&15))
    {
        int c  = threadIdx.x >> 4;
        int nn = threadIdx.x & 15;
        out[(size_t)b * C_ * N_ + (size_t)c * N_ + (pt0 - bB) + nn] = otile[c * 17 + nn];
    }
}

// ---------------------------------------------------------------------------
extern "C" void kernel_launch(void* const* d_in, const int* in_sizes, int n_in,
                              void* d_out, int out_size, void* d_ws, size_t ws_size,
                              hipStream_t stream)
{
    const float* coord = (const float*)d_in[0];
    const float* q     = (const float*)d_in[1];
    const float* k     = (const float*)d_in[2];
    const int*   nbr   = (const int*)d_in[3];
    const float* wq = (const float*)d_in[4];
    const float* bq = (const float*)d_in[5];
    const float* wk = (const float*)d_in[6];
    const float* bk = (const float*)d_in[7];
    const float* wv = (const float*)d_in[8];
    const float* bv = (const float*)d_in[9];
    const float* p1_w = (const float*)d_in[10];
    const float* p1_b = (const float*)d_in[11];
    const float* p_bn_g = (const float*)d_in[12];
    const float* p_bn_b = (const float*)d_in[13];
    const float* p_bn_m = (const float*)d_in[14];
    const float* p_bn_v = (const float*)d_in[15];
    const float* p2_w = (const float*)d_in[16];
    const float* p2_b = (const float*)d_in[17];
    const float* w_bn1_g = (const float*)d_in[18];
    const float* w_bn1_b = (const float*)d_in[19];
    const float* w_bn1_m = (const float*)d_in[20];
    const float* w_bn1_v = (const float*)d_in[21];
    const float* w1_w = (const float*)d_in[22];
    const float* w1_b = (const float*)d_in[23];
    const float* w_bn2_g = (const float*)d_in[24];
    const float* w_bn2_b = (const float*)d_in[25];
    const float* w_bn2_m = (const float*)d_in[26];
    const float* w_bn2_v = (const float*)d_in[27];
    const float* w2_w = (const float*)d_in[28];
    const float* w2_b = (const float*)d_in[29];

    const size_t PTS = (size_t)B_ * N_;        // 40000
    float* ws = (float*)d_ws;
    float* xq2 = ws;                                      // [PTS][64] f32
    unsigned int* kv_t = (unsigned int*)(ws + PTS * C_);  // [PTS][64] packed bf16
    uint4* wtab  = (uint4*)(ws + 2 * PTS * C_);           // 1536 uint4
    uint4* a1tab = wtab + 1536;                           // 128 uint4
    uint2* a2tab = (uint2*)(a1tab + 128);                 // 64 uint2
    float* cz    = (float*)(a2tab + 64);                  // 48 f32

    setup_kernel<<<1, 256, 0, stream>>>(
        wq, wk, wv, w1_w, w1_b, w2_w, w2_b,
        w_bn2_g, w_bn2_b, w_bn2_m, w_bn2_v,
        wtab, a1tab, a2tab, cz);

    proj_kernel<<<(B_ * N_) / 16, 256, 0, stream>>>(
        q, k, coord, bq, bk, bv,
        p1_w, p1_b, p_bn_g, p_bn_b, p_bn_m, p_bn_v, p2_w, p2_b,
        w_bn1_g, w_bn1_b, w_bn1_m, w_bn1_v,
        wtab, xq2, kv_t);

    attn_kernel<<<(B_ * N_) / 16, 1024, 0, stream>>>(
        nbr, xq2, kv_t, a1tab, a2tab, cz,
        (float*)d_out);
}

// Round 9
// 48.069 us; speedup vs baseline: 5.4508x; 1.0274x over previous
//
#include <hip/hip_runtime.h>
#include <hip/hip_bf16.h>
#include <math.h>

#define B_ 2
#define N_ 20000
#define C_ 64
#define K_ 16
#define CS_ 16
#define EPS_ 1e-5f

typedef float f32x4_t  __attribute__((ext_vector_type(4)));
typedef short bf16x8_t __attribute__((ext_vector_type(8)));
typedef short bf16x4_t __attribute__((ext_vector_type(4)));

// bf16 helpers. packbf2 compiles to v_cvt_pk_bf16_f32 (1 instr per pair, RNE)
__device__ __forceinline__ unsigned int packbf2(float a, float b)
{
    union { __hip_bfloat162 h; unsigned int u; } cv;
    cv.h = __float22bfloat162_rn(float2{a, b});
    return cv.u;
}
__device__ __forceinline__ float bf_lo(unsigned int w)
{
    return __builtin_bit_cast(float, w << 16);
}
__device__ __forceinline__ float bf_hi(unsigned int w)
{
    return __builtin_bit_cast(float, w & 0xFFFF0000u);
}
__device__ __forceinline__ void wave_fence()
{
    __builtin_amdgcn_wave_barrier();
}

// ---------------------------------------------------------------------------
// Kernel 0: setup, 6 blocks with disjoint work (runs <1us).
//   wtab[m*512 + og*128 + half*64 + l] (uint4)  bf16 A-frags for wq/wk/wv
//   a1tab[half*64 + l] (uint4), a2tab[l] (uint2)
//   cz[0..15]=zsc, cz[16..31]=zbi, cz[32..47]=tbi
// ---------------------------------------------------------------------------
__global__ __launch_bounds__(256) void setup_kernel(
    const float* __restrict__ wq, const float* __restrict__ wk,
    const float* __restrict__ wv,
    const float* __restrict__ w1_w, const float* __restrict__ w1_b,
    const float* __restrict__ w2_w, const float* __restrict__ w2_b,
    const float* __restrict__ w_bn2_g, const float* __restrict__ w_bn2_b,
    const float* __restrict__ w_bn2_m, const float* __restrict__ w_bn2_v,
    uint4* __restrict__ wtab, uint4* __restrict__ a1tab,
    uint2* __restrict__ a2tab, float* __restrict__ cz)
{
    const int t   = threadIdx.x;
    const int blk = blockIdx.x;
    {   // wtab: 6 blocks x 256 = 1536 entries
        int e = blk * 256 + t;
        int m = e >> 9, rem = e & 511;
        int og = rem >> 7, half = (rem >> 6) & 1, l = rem & 63;
        const float* W = (m == 0) ? wq : ((m == 1) ? wk : wv);
        const float* base = W + (size_t)(og * 16 + (l & 15)) * C_ + half * 32 + (l >> 4) * 8;
        uint4 o;
        o.x = packbf2(base[0], base[1]); o.y = packbf2(base[2], base[3]);
        o.z = packbf2(base[4], base[5]); o.w = packbf2(base[6], base[7]);
        wtab[e] = o;
    }
    if (blk == 0 && t < 128) {
        int half = t >> 6, l = t & 63;
        const float* base = w1_w + (size_t)(l & 15) * C_ + half * 32 + (l >> 4) * 8;
        uint4 o;
        o.x = packbf2(base[0], base[1]); o.y = packbf2(base[2], base[3]);
        o.z = packbf2(base[4], base[5]); o.w = packbf2(base[6], base[7]);
        a1tab[t] = o;
    }
    if (blk == 1 && t < 64) {
        const float* base = w2_w + (t & 15) * 16 + (t >> 4) * 4;
        uint2 o;
        o.x = packbf2(base[0], base[1]); o.y = packbf2(base[2], base[3]);
        a2tab[t] = o;
    }
    if (blk == 2 && t < 16) {
        float s = w_bn2_g[t] * rsqrtf(w_bn2_v[t] + EPS_);
        cz[t]      = s;
        cz[16 + t] = (w1_b[t] - w_bn2_m[t]) * s + w_bn2_b[t];
        cz[32 + t] = w2_b[t];
    }
}

// ---------------------------------------------------------------------------
// Kernel A: projections + positional MLP + bn1 fold, MFMA.
// Outputs:
//   xq2[pt][c]  bf16 of (bn1s*xq - bn1bf)    [w = relu(kvlo - xq2)]
//   kv_t[pt][c] = bf16(bn1s*(xk+pos)) | bf16(xv+pos)<<16
// ---------------------------------------------------------------------------
__global__ __launch_bounds__(256) void proj_kernel(
    const float* __restrict__ q, const float* __restrict__ kin,
    const float* __restrict__ coord,
    const float* __restrict__ bq, const float* __restrict__ bk,
    const float* __restrict__ bv,
    const float* __restrict__ p1_w, const float* __restrict__ p1_b,
    const float* __restrict__ p_bn_g, const float* __restrict__ p_bn_b,
    const float* __restrict__ p_bn_m, const float* __restrict__ p_bn_v,
    const float* __restrict__ p2_w, const float* __restrict__ p2_b,
    const float* __restrict__ w_bn1_g, const float* __restrict__ w_bn1_b,
    const float* __restrict__ w_bn1_m, const float* __restrict__ w_bn1_v,
    const uint4* __restrict__ wtab,
    unsigned int* __restrict__ xq2, unsigned int* __restrict__ kv_t)
{
    constexpr int PS = 26;
    __shared__ unsigned int qp[32 * PS];
    __shared__ unsigned int kp[32 * PS];

    const int t   = threadIdx.x;
    const int og  = __builtin_amdgcn_readfirstlane(t >> 6);
    const int l   = t & 63;
    const int col = l & 15;
    const int qd  = l >> 4;
    const int pt0 = blockIdx.x * 16;
    const int pt  = pt0 + col;
    const int b   = pt0 / N_;
    const int n   = pt - b * N_;
    const size_t cb = (size_t)b * C_ * N_ + n;

    // cooperative input tile (each element loaded once per block)
#pragma unroll
    for (int r = 0; r < 2; r++) {
        int cp = (og << 3) + (qd << 1) + r;
        int ci = cp * 2;
        float q0 = q[cb + (size_t)ci * N_];
        float q1 = q[cb + (size_t)(ci + 1) * N_];
        float k0 = kin[cb + (size_t)ci * N_];
        float k1 = kin[cb + (size_t)(ci + 1) * N_];
        qp[cp * PS + col] = packbf2(q0, q1);
        kp[cp * PS + col] = packbf2(k0, k1);
    }

    union bf8u { bf16x8_t v; uint4 u4; };
    bf8u awq[2], awk[2], awv[2];
#pragma unroll
    for (int half = 0; half < 2; half++) {
        awq[half].u4 = wtab[0 * 512 + og * 128 + half * 64 + l];
        awk[half].u4 = wtab[1 * 512 + og * 128 + half * 64 + l];
        awv[half].u4 = wtab[2 * 512 + og * 128 + half * 64 + l];
    }

    __syncthreads();

    union bf8b { bf16x8_t v; unsigned int u[4]; };
    bf8b bq_[2], bk_[2];
#pragma unroll
    for (int half = 0; half < 2; half++) {
#pragma unroll
        for (int i2 = 0; i2 < 4; i2++) {
            int cp = half * 16 + qd * 4 + i2;
            bq_[half].u[i2] = qp[cp * PS + col];
            bk_[half].u[i2] = kp[cp * PS + col];
        }
    }

    f32x4_t uq = {0.f, 0.f, 0.f, 0.f};
    f32x4_t uv = {0.f, 0.f, 0.f, 0.f};
    f32x4_t uk = {0.f, 0.f, 0.f, 0.f};
    uq = __builtin_amdgcn_mfma_f32_16x16x32_bf16(awq[0].v, bq_[0].v, uq, 0, 0, 0);
    uq = __builtin_amdgcn_mfma_f32_16x16x32_bf16(awq[1].v, bq_[1].v, uq, 0, 0, 0);
    uv = __builtin_amdgcn_mfma_f32_16x16x32_bf16(awv[0].v, bq_[0].v, uv, 0, 0, 0);
    uv = __builtin_amdgcn_mfma_f32_16x16x32_bf16(awv[1].v, bq_[1].v, uv, 0, 0, 0);
    uk = __builtin_amdgcn_mfma_f32_16x16x32_bf16(awk[0].v, bk_[0].v, uk, 0, 0, 0);
    uk = __builtin_amdgcn_mfma_f32_16x16x32_bf16(awk[1].v, bk_[1].v, uk, 0, 0, 0);

    // positional MLP for this point's 4 channels
    float pbs[3], pbb[3];
#pragma unroll
    for (int j = 0; j < 3; j++) {
        float s = p_bn_g[j] * rsqrtf(p_bn_v[j] + EPS_);
        pbs[j] = s;
        pbb[j] = (p1_b[j] - p_bn_m[j]) * s + p_bn_b[j];
    }
    float cx = coord[pt * 3 + 0], cy = coord[pt * 3 + 1], cz = coord[pt * 3 + 2];
    float h0 = fmaxf(0.f, (p1_w[0]*cx + p1_w[1]*cy + p1_w[2]*cz) * pbs[0] + pbb[0]);
    float h1 = fmaxf(0.f, (p1_w[3]*cx + p1_w[4]*cy + p1_w[5]*cz) * pbs[1] + pbb[1]);
    float h2 = fmaxf(0.f, (p1_w[6]*cx + p1_w[7]*cy + p1_w[8]*cz) * pbs[2] + pbb[2]);

    const int ch0 = og * 16 + qd * 4;
    float pos[4];
#pragma unroll
    for (int rr = 0; rr < 4; rr++) {
        int ch = ch0 + rr;
        pos[rr] = fmaf(p2_w[ch*3+0], h0, fmaf(p2_w[ch*3+1], h1,
                  fmaf(p2_w[ch*3+2], h2, p2_b[ch])));
    }

    // epilogue: biases + bn1 fold + packed stores
    const float4 bqv = *reinterpret_cast<const float4*>(bq + ch0);
    const float4 bkv = *reinterpret_cast<const float4*>(bk + ch0);
    const float4 bvv = *reinterpret_cast<const float4*>(bv + ch0);
    const float4 g1  = *reinterpret_cast<const float4*>(w_bn1_g + ch0);
    const float4 b1  = *reinterpret_cast<const float4*>(w_bn1_b + ch0);
    const float4 m1  = *reinterpret_cast<const float4*>(w_bn1_m + ch0);
    const float4 v1  = *reinterpret_cast<const float4*>(w_bn1_v + ch0);

    float xv2[4];
    uint4 kvo;
#pragma unroll
    for (int rr = 0; rr < 4; rr++) {
        float s   = (&g1.x)[rr] * rsqrtf((&v1.x)[rr] + EPS_);
        float b1f = (&b1.x)[rr] - (&m1.x)[rr] * s;
        xv2[rr]   = s * (uq[rr] + (&bqv.x)[rr]) - b1f;      // xq2 value
        float kk  = s * (uk[rr] + (&bkv.x)[rr] + pos[rr]);  // pre-scaled k
        float vv  = uv[rr] + (&bvv.x)[rr] + pos[rr];
        (&kvo.x)[rr] = packbf2(kk, vv);
    }
    uint2 xqo;
    xqo.x = packbf2(xv2[0], xv2[1]);
    xqo.y = packbf2(xv2[2], xv2[3]);
    // xq2 row = 32 uints per point; ch0/2 = index of channel pair
    *reinterpret_cast<uint2*>(xq2 + (size_t)pt * 32 + (ch0 >> 1)) = xqo;
    *reinterpret_cast<uint4*>(kv_t + (size_t)pt * C_ + ch0) = kvo;
}

// ---------------------------------------------------------------------------
// Kernel B: attention via MFMA, fused transposed output (structure as R8,
// packs via v_cvt_pk_bf16_f32, xq2 read as packed bf16 pair).
// ---------------------------------------------------------------------------
#define WROW 72          // ushorts per w-tile row (144B)
#define WPN  (K_ * WROW) // 1152 per point
#define SS4  20          // sfb row stride (f32)
#define SPN  (K_ * SS4)  // 320 per point

__global__ __launch_bounds__(1024, 8) void attn_kernel(
    const int* __restrict__ nbr,
    const unsigned int* __restrict__ xq2, const unsigned int* __restrict__ kv_t,
    const uint4* __restrict__ a1tab, const uint2* __restrict__ a2tab,
    const float* __restrict__ cz,
    float* __restrict__ out)
{
    __shared__ unsigned short wlds_all[16 * WPN];   // 36864B
    __shared__ float          sfb_all[16 * SPN];    // 20480B
    __shared__ float          otile[64 * 17];       //  4352B

    const int w  = __builtin_amdgcn_readfirstlane(threadIdx.x >> 6);
    const int l  = threadIdx.x & 63;
    const int al = l & 15;
    const int qd = l >> 4;
    const int cpair = l & 31;
    const int kh    = l >> 5;
    const int c0    = cpair * 2;

    const int pt0 = blockIdx.x * 16;
    const int b   = pt0 / N_;
    const int bB  = b * N_;
    const int bn  = pt0 + w;

    unsigned short* wlds = wlds_all + w * WPN;
    float*          sfb  = sfb_all + w * SPN;

    // ---- phase 1: gather 8 neighbor rows x 2 channels (issue first) ----
    const int* nb = nbr + (size_t)bn * K_;
    uint2 kvw[8];
#pragma unroll
    for (int j = 0; j < 8; j++) {
        int ia = nb[j];            // wave-uniform -> s_load
        int ib = nb[8 + j];
        int idx = (kh != 0) ? ib : ia;
        kvw[j] = *reinterpret_cast<const uint2*>(kv_t + ((size_t)(bB + idx) * C_ + c0));
    }
    const unsigned int xqu = xq2[(size_t)bn * 32 + cpair];  // bf16 pair
    const float xq0 = bf_lo(xqu);
    const float xq1 = bf_hi(xqu);

    // constants from tables (no per-wave packing)
    union bf8u { bf16x8_t v; uint4 u4; };
    union bf4u { bf16x4_t v; uint2 u2; };
    bf8u a1q0, a1q1; bf4u a2q;
    a1q0.u4 = a1tab[l];
    a1q1.u4 = a1tab[64 + l];
    a2q.u2  = a2tab[l];
    const float4 zsc4 = *reinterpret_cast<const float4*>(cz + qd * 4);
    const float4 zbi4 = *reinterpret_cast<const float4*>(cz + 16 + qd * 4);
    const float4 tbi4 = *reinterpret_cast<const float4*>(cz + 32 + qd * 4);

#pragma unroll
    for (int j = 0; j < 8; j++) {
        float w0 = fmaxf(0.f, bf_lo(kvw[j].x) - xq0);
        float w1 = fmaxf(0.f, bf_lo(kvw[j].y) - xq1);
        *reinterpret_cast<unsigned int*>(wlds + (kh * 8 + j) * WROW + c0) = packbf2(w0, w1);
    }
    wave_fence();

    // ---- phase 2a: u = w1 @ w^T ----
    const bf16x8_t b0 = *reinterpret_cast<const bf16x8_t*>(wlds + al * WROW + qd * 8);
    const bf16x8_t b1 = *reinterpret_cast<const bf16x8_t*>(wlds + al * WROW + 32 + qd * 8);
    f32x4_t u = {0.f, 0.f, 0.f, 0.f};
    u = __builtin_amdgcn_mfma_f32_16x16x32_bf16(a1q0.v, b0, u, 0, 0, 0);
    u = __builtin_amdgcn_mfma_f32_16x16x32_bf16(a1q1.v, b1, u, 0, 0, 0);

    union { bf16x4_t v; unsigned int u2[2]; } zb;
    {
        float z0 = fmaxf(0.f, u[0] * zsc4.x + zbi4.x);
        float z1 = fmaxf(0.f, u[1] * zsc4.y + zbi4.y);
        float z2 = fmaxf(0.f, u[2] * zsc4.z + zbi4.z);
        float z3 = fmaxf(0.f, u[3] * zsc4.w + zbi4.w);
        zb.u2[0] = packbf2(z0, z1);
        zb.u2[1] = packbf2(z2, z3);
    }

    // ---- phase 2b: t = w2 @ z ----
    f32x4_t t4 = {0.f, 0.f, 0.f, 0.f};
    t4 = __builtin_amdgcn_mfma_f32_16x16x16bf16_1k(a2q.v, zb.v, t4, 0, 0, 0);

    // ---- softmax over neighbors, rows g = 4qd+rr, col k = al ----
    float4 sv;
#pragma unroll
    for (int rr = 0; rr < 4; rr++) {
        float e = __expf(t4[rr] + (&tbi4.x)[rr]);   // |t| << 80, no max-sub
        float s = e;
        s += __shfl_xor(s, 1);
        s += __shfl_xor(s, 2);
        s += __shfl_xor(s, 4);
        s += __shfl_xor(s, 8);
        (&sv.x)[rr] = e * __builtin_amdgcn_rcpf(s);
    }
    *reinterpret_cast<float4*>(sfb + al * SS4 + qd * 4) = sv;  // [k][g] row al
    wave_fence();

    // ---- phase 3: out[c] = sum_k v[k][c] * soft[k][c&15] ----
    const int g0 = c0 & 15;
    float acc0 = 0.f, acc1 = 0.f;
#pragma unroll
    for (int j = 0; j < 8; j++) {
        float2 sp = *reinterpret_cast<const float2*>(sfb + (kh * 8 + j) * SS4 + g0);
        acc0 = fmaf(bf_hi(kvw[j].x), sp.x, acc0);
        acc1 = fmaf(bf_hi(kvw[j].y), sp.y, acc1);
    }
    acc0 += __shfl_xor(acc0, 32);
    acc1 += __shfl_xor(acc1, 32);
    if (kh == 0) {
        otile[c0 * 17 + w]       = acc0;
        otile[(c0 + 1) * 17 + w] = acc1;
    }
    __syncthreads();

    // coalesced [B,C,N] write
    {
        int c  = threadIdx.x >> 4;
        int nn = threadIdx.x & 15;
        out[(size_t)b * C_ * N_ + (size_t)c * N_ + (pt0 - bB) + nn] = otile[c * 17 + nn];
    }
}

// ---------------------------------------------------------------------------
extern "C" void kernel_launch(void* const* d_in, const int* in_sizes, int n_in,
                              void* d_out, int out_size, void* d_ws, size_t ws_size,
                              hipStream_t stream)
{
    const float* coord = (const float*)d_in[0];
    const float* q     = (const float*)d_in[1];
    const float* k     = (const float*)d_in[2];
    const int*   nbr   = (const int*)d_in[3];
    const float* wq = (const float*)d_in[4];
    const float* bq = (const float*)d_in[5];
    const float* wk = (const float*)d_in[6];
    const float* bk = (const float*)d_in[7];
    const float* wv = (const float*)d_in[8];
    const float* bv = (const float*)d_in[9];
    const float* p1_w = (const float*)d_in[10];
    const float* p1_b = (const float*)d_in[11];
    const float* p_bn_g = (const float*)d_in[12];
    const float* p_bn_b = (const float*)d_in[13];
    const float* p_bn_m = (const float*)d_in[14];
    const float* p_bn_v = (const float*)d_in[15];
    const float* p2_w = (const float*)d_in[16];
    const float* p2_b = (const float*)d_in[17];
    const float* w_bn1_g = (const float*)d_in[18];
    const float* w_bn1_b = (const float*)d_in[19];
    const float* w_bn1_m = (const float*)d_in[20];
    const float* w_bn1_v = (const float*)d_in[21];
    const float* w1_w = (const float*)d_in[22];
    const float* w1_b = (const float*)d_in[23];
    const float* w_bn2_g = (const float*)d_in[24];
    const float* w_bn2_b = (const float*)d_in[25];
    const float* w_bn2_m = (const float*)d_in[26];
    const float* w_bn2_v = (const float*)d_in[27];
    const float* w2_w = (const float*)d_in[28];
    const float* w2_b = (const float*)d_in[29];

    const size_t PTS = (size_t)B_ * N_;        // 40000
    char* wsb = (char*)d_ws;
    unsigned int* kv_t = (unsigned int*)wsb;                    // [PTS][64] u32 (10.24MB)
    unsigned int* xq2  = (unsigned int*)(wsb + PTS * C_ * 4);   // [PTS][32] u32 bf16 pairs (5.12MB)
    uint4* wtab  = (uint4*)(wsb + PTS * C_ * 4 + PTS * C_ * 2); // 1536 uint4
    uint4* a1tab = wtab + 1536;                                 // 128 uint4
    uint2* a2tab = (uint2*)(a1tab + 128);                       // 64 uint2
    float* cz    = (float*)(a2tab + 64);                        // 48 f32

    setup_kernel<<<6, 256, 0, stream>>>(
        wq, wk, wv, w1_w, w1_b, w2_w, w2_b,
        w_bn2_g, w_bn2_b, w_bn2_m, w_bn2_v,
        wtab, a1tab, a2tab, cz);

    proj_kernel<<<(B_ * N_) / 16, 256, 0, stream>>>(
        q, k, coord, bq, bk, bv,
        p1_w, p1_b, p_bn_g, p_bn_b, p_bn_m, p_bn_v, p2_w, p2_b,
        w_bn1_g, w_bn1_b, w_bn1_m, w_bn1_v,
        wtab, xq2, kv_t);

    attn_kernel<<<(B_ * N_) / 16, 1024, 0, stream>>>(
        nbr, xq2, kv_t, a1tab, a2tab, cz,
        (float*)d_out);
}

// Round 10
// 47.123 us; speedup vs baseline: 5.5603x; 1.0201x over previous
//
#include <hip/hip_runtime.h>
#include <hip/hip_bf16.h>
#include <math.h>

#define B_ 2
#define N_ 20000
#define C_ 64
#define K_ 16
#define CS_ 16
#define EPS_ 1e-5f

typedef float f32x4_t  __attribute__((ext_vector_type(4)));
typedef short bf16x8_t __attribute__((ext_vector_type(8)));
typedef short bf16x4_t __attribute__((ext_vector_type(4)));

__device__ __forceinline__ unsigned int packbf2(float a, float b)
{
    union { __hip_bfloat162 h; unsigned int u; } cv;
    cv.h = __float22bfloat162_rn(float2{a, b});
    return cv.u;
}
__device__ __forceinline__ float bf_lo(unsigned int w)
{
    return __builtin_bit_cast(float, w << 16);
}
__device__ __forceinline__ float bf_hi(unsigned int w)
{
    return __builtin_bit_cast(float, w & 0xFFFF0000u);
}
__device__ __forceinline__ void wave_fence()
{
    __builtin_amdgcn_wave_barrier();
}

// ---------------------------------------------------------------------------
// Kernel 0: setup, 6 blocks, disjoint work.
//   wtab[m*512+og*128+half*64+l] (uint4)  bf16 A-frags wq/wk/wv
//   a1tab[half*64+l] (uint4), a2tab[l] (uint2)
//   cz[0..15]=zsc, cz[16..31]=zbi, cz[32..47]=tbi
//   ctab[ch] = {bn1s, bn1s*bq-b1f, bk, bv}   (proj epilogue constants)
//   ptab[ch] = {p2w0, p2w1, p2w2, p2b}       (pos-MLP layer-2 row)
// ---------------------------------------------------------------------------
__global__ __launch_bounds__(256) void setup_kernel(
    const float* __restrict__ wq, const float* __restrict__ wk,
    const float* __restrict__ wv,
    const float* __restrict__ bq, const float* __restrict__ bk,
    const float* __restrict__ bv,
    const float* __restrict__ w1_w, const float* __restrict__ w1_b,
    const float* __restrict__ w2_w, const float* __restrict__ w2_b,
    const float* __restrict__ w_bn1_g, const float* __restrict__ w_bn1_b,
    const float* __restrict__ w_bn1_m, const float* __restrict__ w_bn1_v,
    const float* __restrict__ w_bn2_g, const float* __restrict__ w_bn2_b,
    const float* __restrict__ w_bn2_m, const float* __restrict__ w_bn2_v,
    const float* __restrict__ p2_w, const float* __restrict__ p2_b,
    uint4* __restrict__ wtab, uint4* __restrict__ a1tab,
    uint2* __restrict__ a2tab, float* __restrict__ cz,
    float4* __restrict__ ctab, float4* __restrict__ ptab)
{
    const int t   = threadIdx.x;
    const int blk = blockIdx.x;
    {   // wtab: 6 blocks x 256 = 1536 entries
        int e = blk * 256 + t;
        int m = e >> 9, rem = e & 511;
        int og = rem >> 7, half = (rem >> 6) & 1, l = rem & 63;
        const float* W = (m == 0) ? wq : ((m == 1) ? wk : wv);
        const float* base = W + (size_t)(og * 16 + (l & 15)) * C_ + half * 32 + (l >> 4) * 8;
        uint4 o;
        o.x = packbf2(base[0], base[1]); o.y = packbf2(base[2], base[3]);
        o.z = packbf2(base[4], base[5]); o.w = packbf2(base[6], base[7]);
        wtab[e] = o;
    }
    if (blk == 0 && t < 128) {
        int half = t >> 6, l = t & 63;
        const float* base = w1_w + (size_t)(l & 15) * C_ + half * 32 + (l >> 4) * 8;
        uint4 o;
        o.x = packbf2(base[0], base[1]); o.y = packbf2(base[2], base[3]);
        o.z = packbf2(base[4], base[5]); o.w = packbf2(base[6], base[7]);
        a1tab[t] = o;
    }
    if (blk == 1 && t < 64) {
        const float* base = w2_w + (t & 15) * 16 + (t >> 4) * 4;
        uint2 o;
        o.x = packbf2(base[0], base[1]); o.y = packbf2(base[2], base[3]);
        a2tab[t] = o;
    }
    if (blk == 2 && t < 16) {
        float s = w_bn2_g[t] * rsqrtf(w_bn2_v[t] + EPS_);
        cz[t]      = s;
        cz[16 + t] = (w1_b[t] - w_bn2_m[t]) * s + w_bn2_b[t];
        cz[32 + t] = w2_b[t];
    }
    if (blk == 3 && t < 64) {
        float s   = w_bn1_g[t] * rsqrtf(w_bn1_v[t] + EPS_);
        float b1f = w_bn1_b[t] - w_bn1_m[t] * s;
        ctab[t] = float4{s, s * bq[t] - b1f, bk[t], bv[t]};
    }
    if (blk == 4 && t < 64) {
        ptab[t] = float4{p2_w[t*3+0], p2_w[t*3+1], p2_w[t*3+2], p2_b[t]};
    }
}

// ---------------------------------------------------------------------------
// Kernel A: projections + positional MLP + bn1 fold, MFMA.
// Epilogue constants come from ctab/ptab (8 float4 loads, no per-wave rsqrt).
//   xq2[pt][c]  bf16 of (bn1s*xq - bn1bf)
//   kv_t[pt][c] = bf16(bn1s*(xk+pos)) | bf16(xv+pos)<<16
// ---------------------------------------------------------------------------
__global__ __launch_bounds__(256) void proj_kernel(
    const float* __restrict__ q, const float* __restrict__ kin,
    const float* __restrict__ coord,
    const float* __restrict__ p1_w, const float* __restrict__ p1_b,
    const float* __restrict__ p_bn_g, const float* __restrict__ p_bn_b,
    const float* __restrict__ p_bn_m, const float* __restrict__ p_bn_v,
    const uint4* __restrict__ wtab,
    const float4* __restrict__ ctab, const float4* __restrict__ ptab,
    unsigned int* __restrict__ xq2, unsigned int* __restrict__ kv_t)
{
    constexpr int PS = 26;
    __shared__ unsigned int qp[32 * PS];
    __shared__ unsigned int kp[32 * PS];

    const int t   = threadIdx.x;
    const int og  = __builtin_amdgcn_readfirstlane(t >> 6);
    const int l   = t & 63;
    const int col = l & 15;
    const int qd  = l >> 4;
    const int pt0 = blockIdx.x * 16;
    const int pt  = pt0 + col;
    const int b   = pt0 / N_;
    const int n   = pt - b * N_;
    const size_t cb = (size_t)b * C_ * N_ + n;

    // cooperative input tile (each element loaded once per block)
#pragma unroll
    for (int r = 0; r < 2; r++) {
        int cp = (og << 3) + (qd << 1) + r;
        int ci = cp * 2;
        float q0 = q[cb + (size_t)ci * N_];
        float q1 = q[cb + (size_t)(ci + 1) * N_];
        float k0 = kin[cb + (size_t)ci * N_];
        float k1 = kin[cb + (size_t)(ci + 1) * N_];
        qp[cp * PS + col] = packbf2(q0, q1);
        kp[cp * PS + col] = packbf2(k0, k1);
    }

    union bf8u { bf16x8_t v; uint4 u4; };
    bf8u awq[2], awk[2], awv[2];
#pragma unroll
    for (int half = 0; half < 2; half++) {
        awq[half].u4 = wtab[0 * 512 + og * 128 + half * 64 + l];
        awk[half].u4 = wtab[1 * 512 + og * 128 + half * 64 + l];
        awv[half].u4 = wtab[2 * 512 + og * 128 + half * 64 + l];
    }

    __syncthreads();

    union bf8b { bf16x8_t v; unsigned int u[4]; };
    bf8b bq_[2], bk_[2];
#pragma unroll
    for (int half = 0; half < 2; half++) {
#pragma unroll
        for (int i2 = 0; i2 < 4; i2++) {
            int cp = half * 16 + qd * 4 + i2;
            bq_[half].u[i2] = qp[cp * PS + col];
            bk_[half].u[i2] = kp[cp * PS + col];
        }
    }

    f32x4_t uq = {0.f, 0.f, 0.f, 0.f};
    f32x4_t uv = {0.f, 0.f, 0.f, 0.f};
    f32x4_t uk = {0.f, 0.f, 0.f, 0.f};
    uq = __builtin_amdgcn_mfma_f32_16x16x32_bf16(awq[0].v, bq_[0].v, uq, 0, 0, 0);
    uq = __builtin_amdgcn_mfma_f32_16x16x32_bf16(awq[1].v, bq_[1].v, uq, 0, 0, 0);
    uv = __builtin_amdgcn_mfma_f32_16x16x32_bf16(awv[0].v, bq_[0].v, uv, 0, 0, 0);
    uv = __builtin_amdgcn_mfma_f32_16x16x32_bf16(awv[1].v, bq_[1].v, uv, 0, 0, 0);
    uk = __builtin_amdgcn_mfma_f32_16x16x32_bf16(awk[0].v, bk_[0].v, uk, 0, 0, 0);
    uk = __builtin_amdgcn_mfma_f32_16x16x32_bf16(awk[1].v, bk_[1].v, uk, 0, 0, 0);

    // positional MLP layer 1 (wave-uniform weights -> s_loads)
    float pbs[3], pbb[3];
#pragma unroll
    for (int j = 0; j < 3; j++) {
        float s = p_bn_g[j] * rsqrtf(p_bn_v[j] + EPS_);
        pbs[j] = s;
        pbb[j] = (p1_b[j] - p_bn_m[j]) * s + p_bn_b[j];
    }
    float cx = coord[pt * 3 + 0], cy = coord[pt * 3 + 1], cz = coord[pt * 3 + 2];
    float h0 = fmaxf(0.f, (p1_w[0]*cx + p1_w[1]*cy + p1_w[2]*cz) * pbs[0] + pbb[0]);
    float h1 = fmaxf(0.f, (p1_w[3]*cx + p1_w[4]*cy + p1_w[5]*cz) * pbs[1] + pbb[1]);
    float h2 = fmaxf(0.f, (p1_w[6]*cx + p1_w[7]*cy + p1_w[8]*cz) * pbs[2] + pbb[2]);

    // epilogue via tables
    const int ch0 = og * 16 + qd * 4;
    float xv2[4];
    uint4 kvo;
#pragma unroll
    for (int rr = 0; rr < 4; rr++) {
        const float4 ct  = ctab[ch0 + rr];
        const float4 pt4 = ptab[ch0 + rr];
        float pos = fmaf(pt4.x, h0, fmaf(pt4.y, h1, fmaf(pt4.z, h2, pt4.w)));
        xv2[rr]   = fmaf(ct.x, uq[rr], ct.y);
        float kk  = ct.x * (uk[rr] + ct.z + pos);
        float vv  = uv[rr] + ct.w + pos;
        (&kvo.x)[rr] = packbf2(kk, vv);
    }
    uint2 xqo;
    xqo.x = packbf2(xv2[0], xv2[1]);
    xqo.y = packbf2(xv2[2], xv2[3]);
    *reinterpret_cast<uint2*>(xq2 + (size_t)pt * 32 + (ch0 >> 1)) = xqo;
    *reinterpret_cast<uint4*>(kv_t + (size_t)pt * C_ + ch0) = kvo;
}

// ---------------------------------------------------------------------------
// Kernel B: attention via MFMA, fused transposed output.
// Block = 512 thr = 8 waves = 8 points (was 1024/16): same 32 waves/CU
// (30976B LDS -> 4 blocks/CU) but half the barrier domain and finer drain.
// ---------------------------------------------------------------------------
#define WROW 72          // ushorts per w-tile row (144B)
#define WPN  (K_ * WROW) // 1152 per point
#define SS4  20          // sfb row stride (f32)
#define SPN  (K_ * SS4)  // 320 per point

__global__ __launch_bounds__(512, 8) void attn_kernel(
    const int* __restrict__ nbr,
    const unsigned int* __restrict__ xq2, const unsigned int* __restrict__ kv_t,
    const uint4* __restrict__ a1tab, const uint2* __restrict__ a2tab,
    const float* __restrict__ cz,
    float* __restrict__ out)
{
    __shared__ unsigned short wlds_all[8 * WPN];   // 18432B
    __shared__ float          sfb_all[8 * SPN];    // 10240B
    __shared__ float          otile[64 * 9];       //  2304B

    const int w  = __builtin_amdgcn_readfirstlane(threadIdx.x >> 6);
    const int l  = threadIdx.x & 63;
    const int al = l & 15;
    const int qd = l >> 4;
    const int cpair = l & 31;
    const int kh    = l >> 5;
    const int c0    = cpair * 2;

    const int pt0 = blockIdx.x * 8;       // 5000 blocks; 20000%8==0, no straddle
    const int b   = pt0 / N_;
    const int bB  = b * N_;
    const int bn  = pt0 + w;

    unsigned short* wlds = wlds_all + w * WPN;
    float*          sfb  = sfb_all + w * SPN;

    // ---- phase 1: gather 8 neighbor rows x 2 channels (issue first) ----
    const int* nb = nbr + (size_t)bn * K_;
    uint2 kvw[8];
#pragma unroll
    for (int j = 0; j < 8; j++) {
        int ia = nb[j];            // wave-uniform -> s_load
        int ib = nb[8 + j];
        int idx = (kh != 0) ? ib : ia;
        kvw[j] = *reinterpret_cast<const uint2*>(kv_t + ((size_t)(bB + idx) * C_ + c0));
    }
    const unsigned int xqu = xq2[(size_t)bn * 32 + cpair];  // bf16 pair
    const float xq0 = bf_lo(xqu);
    const float xq1 = bf_hi(xqu);

    // constants from tables (no per-wave packing)
    union bf8u { bf16x8_t v; uint4 u4; };
    union bf4u { bf16x4_t v; uint2 u2; };
    bf8u a1q0, a1q1; bf4u a2q;
    a1q0.u4 = a1tab[l];
    a1q1.u4 = a1tab[64 + l];
    a2q.u2  = a2tab[l];
    const float4 zsc4 = *reinterpret_cast<const float4*>(cz + qd * 4);
    const float4 zbi4 = *reinterpret_cast<const float4*>(cz + 16 + qd * 4);
    const float4 tbi4 = *reinterpret_cast<const float4*>(cz + 32 + qd * 4);

#pragma unroll
    for (int j = 0; j < 8; j++) {
        float w0 = fmaxf(0.f, bf_lo(kvw[j].x) - xq0);
        float w1 = fmaxf(0.f, bf_lo(kvw[j].y) - xq1);
        *reinterpret_cast<unsigned int*>(wlds + (kh * 8 + j) * WROW + c0) = packbf2(w0, w1);
    }
    wave_fence();

    // ---- phase 2a: u = w1 @ w^T ----
    const bf16x8_t b0 = *reinterpret_cast<const bf16x8_t*>(wlds + al * WROW + qd * 8);
    const bf16x8_t b1 = *reinterpret_cast<const bf16x8_t*>(wlds + al * WROW + 32 + qd * 8);
    f32x4_t u = {0.f, 0.f, 0.f, 0.f};
    u = __builtin_amdgcn_mfma_f32_16x16x32_bf16(a1q0.v, b0, u, 0, 0, 0);
    u = __builtin_amdgcn_mfma_f32_16x16x32_bf16(a1q1.v, b1, u, 0, 0, 0);

    union { bf16x4_t v; unsigned int u2[2]; } zb;
    {
        float z0 = fmaxf(0.f, u[0] * zsc4.x + zbi4.x);
        float z1 = fmaxf(0.f, u[1] * zsc4.y + zbi4.y);
        float z2 = fmaxf(0.f, u[2] * zsc4.z + zbi4.z);
        float z3 = fmaxf(0.f, u[3] * zsc4.w + zbi4.w);
        zb.u2[0] = packbf2(z0, z1);
        zb.u2[1] = packbf2(z2, z3);
    }

    // ---- phase 2b: t = w2 @ z ----
    f32x4_t t4 = {0.f, 0.f, 0.f, 0.f};
    t4 = __builtin_amdgcn_mfma_f32_16x16x16bf16_1k(a2q.v, zb.v, t4, 0, 0, 0);

    // ---- softmax over neighbors, rows g = 4qd+rr, col k = al ----
    float4 sv;
#pragma unroll
    for (int rr = 0; rr < 4; rr++) {
        float e = __expf(t4[rr] + (&tbi4.x)[rr]);   // |t| << 80, no max-sub
        float s = e;
        s += __shfl_xor(s, 1);
        s += __shfl_xor(s, 2);
        s += __shfl_xor(s, 4);
        s += __shfl_xor(s, 8);
        (&sv.x)[rr] = e * __builtin_amdgcn_rcpf(s);
    }
    *reinterpret_cast<float4*>(sfb + al * SS4 + qd * 4) = sv;  // [k][g] row al
    wave_fence();

    // ---- phase 3: out[c] = sum_k v[k][c] * soft[k][c&15] ----
    const int g0 = c0 & 15;
    float acc0 = 0.f, acc1 = 0.f;
#pragma unroll
    for (int j = 0; j < 8; j++) {
        float2 sp = *reinterpret_cast<const float2*>(sfb + (kh * 8 + j) * SS4 + g0);
        acc0 = fmaf(bf_hi(kvw[j].x), sp.x, acc0);
        acc1 = fmaf(bf_hi(kvw[j].y), sp.y, acc1);
    }
    acc0 += __shfl_xor(acc0, 32);
    acc1 += __shfl_xor(acc1, 32);
    if (kh == 0) {
        otile[c0 * 9 + w]       = acc0;
        otile[(c0 + 1) * 9 + w] = acc1;
    }
    __syncthreads();

    // coalesced [B,C,N] write: thread t -> (c = t>>3, n = pt0%N + (t&7))
    {
        int c  = threadIdx.x >> 3;
        int nn = threadIdx.x & 7;
        out[(size_t)b * C_ * N_ + (size_t)c * N_ + (pt0 - bB) + nn] = otile[c * 9 + nn];
    }
}

// ---------------------------------------------------------------------------
extern "C" void kernel_launch(void* const* d_in, const int* in_sizes, int n_in,
                              void* d_out, int out_size, void* d_ws, size_t ws_size,
                              hipStream_t stream)
{
    const float* coord = (const float*)d_in[0];
    const float* q     = (const float*)d_in[1];
    const float* k     = (const float*)d_in[2];
    const int*   nbr   = (const int*)d_in[3];
    const float* wq = (const float*)d_in[4];
    const float* bq = (const float*)d_in[5];
    const float* wk = (const float*)d_in[6];
    const float* bk = (const float*)d_in[7];
    const float* wv = (const float*)d_in[8];
    const float* bv = (const float*)d_in[9];
    const float* p1_w = (const float*)d_in[10];
    const float* p1_b = (const float*)d_in[11];
    const float* p_bn_g = (const float*)d_in[12];
    const float* p_bn_b = (const float*)d_in[13];
    const float* p_bn_m = (const float*)d_in[14];
    const float* p_bn_v = (const float*)d_in[15];
    const float* p2_w = (const float*)d_in[16];
    const float* p2_b = (const float*)d_in[17];
    const float* w_bn1_g = (const float*)d_in[18];
    const float* w_bn1_b = (const float*)d_in[19];
    const float* w_bn1_m = (const float*)d_in[20];
    const float* w_bn1_v = (const float*)d_in[21];
    const float* w1_w = (const float*)d_in[22];
    const float* w1_b = (const float*)d_in[23];
    const float* w_bn2_g = (const float*)d_in[24];
    const float* w_bn2_b = (const float*)d_in[25];
    const float* w_bn2_m = (const float*)d_in[26];
    const float* w_bn2_v = (const float*)d_in[27];
    const float* w2_w = (const float*)d_in[28];
    const float* w2_b = (const float*)d_in[29];

    const size_t PTS = (size_t)B_ * N_;        // 40000
    char* wsb = (char*)d_ws;
    unsigned int* kv_t = (unsigned int*)wsb;                    // [PTS][64] u32 (10.24MB)
    unsigned int* xq2  = (unsigned int*)(wsb + PTS * C_ * 4);   // [PTS][32] u32 (5.12MB)
    uint4* wtab  = (uint4*)(wsb + PTS * C_ * 4 + PTS * C_ * 2); // 1536 uint4
    uint4* a1tab = wtab + 1536;                                 // 128 uint4
    uint2* a2tab = (uint2*)(a1tab + 128);                       // 64 uint2
    float* cz    = (float*)(a2tab + 64);                        // 48 f32
    float4* ctab = (float4*)(cz + 48);                          // 64 float4
    float4* ptab = ctab + 64;                                   // 64 float4

    setup_kernel<<<6, 256, 0, stream>>>(
        wq, wk, wv, bq, bk, bv, w1_w, w1_b, w2_w, w2_b,
        w_bn1_g, w_bn1_b, w_bn1_m, w_bn1_v,
        w_bn2_g, w_bn2_b, w_bn2_m, w_bn2_v,
        p2_w, p2_b,
        wtab, a1tab, a2tab, cz, ctab, ptab);

    proj_kernel<<<(B_ * N_) / 16, 256, 0, stream>>>(
        q, k, coord,
        p1_w, p1_b, p_bn_g, p_bn_b, p_bn_m, p_bn_v,
        wtab, ctab, ptab, xq2, kv_t);

    attn_kernel<<<(B_ * N_) / 8, 512, 0, stream>>>(
        nbr, xq2, kv_t, a1tab, a2tab, cz,
        (float*)d_out);
}